// Round 1
// baseline (1014.618 us; speedup 1.0000x reference)
//
#include <hip/hip_runtime.h>
#include <math.h>

// Problem constants: B=2, T=1024, C=1024, NH=16, HS=64, BD=16, HORIZON=64.

__device__ __forceinline__ float gelu_exact(float z) {
    return 0.5f * z * (1.0f + erff(z * 0.70710678118654752f));
}

// C = A @ B + bias ; A: MxK row-major, B: KxN row-major, C: MxN row-major.
// M,N multiples of 64; K multiple of 16. 256 threads, 64x64 tile, 4x4/thread.
__global__ __launch_bounds__(256) void gemm_bias_kernel(
    const float* __restrict__ A, const float* __restrict__ B,
    const float* __restrict__ bias, float* __restrict__ C,
    int M, int N, int K)
{
    __shared__ float As[16][68];   // transposed A tile, padded (+4 keeps float4 alignment)
    __shared__ float Bs[16][64];
    const int tid = threadIdx.x;
    const int tx = tid & 15;
    const int ty = tid >> 4;
    const int rowbase = blockIdx.y * 64;
    const int colbase = blockIdx.x * 64;
    float acc[4][4] = {};

    for (int k0 = 0; k0 < K; k0 += 16) {
        {
            const int r  = tid >> 2;           // 0..63
            const int c4 = (tid & 3) << 2;     // 0,4,8,12
            const float4 a = *reinterpret_cast<const float4*>(
                A + (size_t)(rowbase + r) * K + k0 + c4);
            As[c4 + 0][r] = a.x; As[c4 + 1][r] = a.y;
            As[c4 + 2][r] = a.z; As[c4 + 3][r] = a.w;
        }
        {
            const int kr = tid >> 4;           // 0..15
            const int c4 = (tid & 15) << 2;    // 0..60
            *reinterpret_cast<float4*>(&Bs[kr][c4]) =
                *reinterpret_cast<const float4*>(
                    B + (size_t)(k0 + kr) * N + colbase + c4);
        }
        __syncthreads();
        #pragma unroll
        for (int k = 0; k < 16; ++k) {
            const float4 av = *reinterpret_cast<const float4*>(&As[k][ty * 4]);
            const float4 bv = *reinterpret_cast<const float4*>(&Bs[k][tx * 4]);
            const float a0[4] = {av.x, av.y, av.z, av.w};
            const float b0[4] = {bv.x, bv.y, bv.z, bv.w};
            #pragma unroll
            for (int i = 0; i < 4; ++i)
                #pragma unroll
                for (int jj = 0; jj < 4; ++jj)
                    acc[i][jj] += a0[i] * b0[jj];
        }
        __syncthreads();
    }
    #pragma unroll
    for (int i = 0; i < 4; ++i) {
        const int row = rowbase + ty * 4 + i;
        float* crow = C + (size_t)row * N + colbase;
        #pragma unroll
        for (int jj = 0; jj < 4; ++jj)
            crow[tx * 4 + jj] = acc[i][jj] + bias[colbase + tx * 4 + jj];
    }
}

// One wave per (b,h,t). Lane j computes logit for window slot j; 64-lane
// softmax via shuffles; PV: lane k accumulates output channel k.
__global__ __launch_bounds__(256) void attn_win_kernel(
    const float* __restrict__ disp,   // (B*T, NH*BD=256)
    const float* __restrict__ val,    // (B*T, C=1024)
    const float* __restrict__ rel,    // (64,16)
    const float* __restrict__ Wpos,   // (16,16)
    const float* __restrict__ Wfused, // (16,32)
    const float* __restrict__ bfused, // (32)
    const float* __restrict__ Wbond,  // (16)
    const float* __restrict__ bbond,  // (1)
    const float* __restrict__ Wdmg,   // (16)
    const float* __restrict__ bdmg,   // (1)
    float* __restrict__ attn)         // (B*T, C=1024)
{
    __shared__ float posf[64][17];    // +1 pad: kills 16-stride bank conflict
    __shared__ float wf[16][32];
    __shared__ float sbias[32];
    __shared__ float wbd[16];
    __shared__ float wdm[16];
    const int tid = threadIdx.x;

    for (int i = tid; i < 512; i += 256) ((float*)wf)[i] = Wfused[i];
    if (tid < 32) sbias[tid] = bfused[tid];
    if (tid < 16) { wbd[tid] = Wbond[tid]; wdm[tid] = Wdmg[tid]; }
    for (int n = tid; n < 1024; n += 256) {
        const int j = n >> 4, e = n & 15;
        float s = 0.f;
        #pragma unroll
        for (int k = 0; k < 16; ++k) s += rel[j * 16 + k] * Wpos[k * 16 + e];
        posf[j][e] = s;
    }
    __syncthreads();
    const float bb = bbond[0];
    const float bd = bdmg[0];

    const int wave = tid >> 6;
    const int lane = tid & 63;
    const int gw = blockIdx.x * 4 + wave;   // 0..32767 = (b*16+h)*1024 + t
    const int t  = gw & 1023;
    const int bh = gw >> 10;
    const int h  = bh & 15;
    const int b  = bh >> 4;
    const int row_t = b * 1024 + t;

    const float* dt = disp + (size_t)row_t * 256 + h * 16;
    const int j    = lane;
    const int tsrc = t + j - 63;
    const int rs   = b * 1024 + (tsrc < 0 ? 0 : tsrc);
    const float* dw = disp + (size_t)rs * 256 + h * 16;

    float strain[16];
    #pragma unroll
    for (int d = 0; d < 16; ++d) strain[d] = dw[d] - dt[d];

    float bf[16], df[16];
    #pragma unroll
    for (int e = 0; e < 16; ++e) { bf[e] = sbias[e]; df[e] = sbias[16 + e]; }
    #pragma unroll
    for (int d = 0; d < 16; ++d) {
        const float s = strain[d];
        #pragma unroll
        for (int e = 0; e < 16; ++e) {
            bf[e] += s * wf[d][e];
            df[e] += s * wf[d][16 + e];
        }
    }
    float bond = bb, dmg = bd;
    #pragma unroll
    for (int e = 0; e < 16; ++e) {
        bond += gelu_exact(bf[e] + posf[j][e]) * wbd[e];
        dmg  += gelu_exact(df[e]) * wdm[e];
    }
    const float damage = 1.0f / (1.0f + __expf(-dmg));
    float logit = bond - 10.0f * damage;
    if (tsrc < 0) logit = -INFINITY;

    // 64-lane softmax
    float m = logit;
    #pragma unroll
    for (int o = 32; o; o >>= 1) m = fmaxf(m, __shfl_xor(m, o));
    const float p = __expf(logit - m);   // exp(-inf)=0 for masked lanes
    float ssum = p;
    #pragma unroll
    for (int o = 32; o; o >>= 1) ssum += __shfl_xor(ssum, o);
    const float w = p / ssum;

    // PV: lane = output channel k; val row reads are coalesced (64 contiguous).
    float acc = 0.f;
    const float* vbase = val + (size_t)(b * 1024) * 1024 + h * 64 + lane;
    const int j0 = (t >= 63) ? 0 : (63 - t);
    for (int jj = j0; jj < 64; ++jj) {
        const float wj = __shfl(w, jj);
        acc += wj * vbase[(size_t)(t + jj - 63) * 1024];
    }
    attn[(size_t)row_t * 1024 + h * 64 + lane] = acc;
}

extern "C" void kernel_launch(void* const* d_in, const int* in_sizes, int n_in,
                              void* d_out, int out_size, void* d_ws, size_t ws_size,
                              hipStream_t stream) {
    const float* x       = (const float*)d_in[0];
    const float* W_disp  = (const float*)d_in[1];
    const float* b_disp  = (const float*)d_in[2];
    const float* W_val   = (const float*)d_in[3];
    const float* b_val   = (const float*)d_in[4];
    const float* rel     = (const float*)d_in[5];
    const float* W_fused = (const float*)d_in[6];
    const float* b_fused = (const float*)d_in[7];
    const float* W_pos   = (const float*)d_in[8];
    const float* W_bond  = (const float*)d_in[9];
    const float* b_bond  = (const float*)d_in[10];
    const float* W_dmg   = (const float*)d_in[11];
    const float* b_dmg   = (const float*)d_in[12];
    const float* W_cproj = (const float*)d_in[13];
    const float* b_cproj = (const float*)d_in[14];
    float* out = (float*)d_out;

    // Workspace layout (fp32): disp 2048*256, val 2048*1024, attn 2048*1024
    float* disp = (float*)d_ws;
    float* val  = disp + 2048 * 256;
    float* attn = val  + 2048 * 1024;

    dim3 blk(256);
    gemm_bias_kernel<<<dim3(256 / 64, 2048 / 64), blk, 0, stream>>>(
        x, W_disp, b_disp, disp, 2048, 256, 1024);
    gemm_bias_kernel<<<dim3(1024 / 64, 2048 / 64), blk, 0, stream>>>(
        x, W_val, b_val, val, 2048, 1024, 1024);
    attn_win_kernel<<<dim3(8192), blk, 0, stream>>>(
        disp, val, rel, W_pos, W_fused, b_fused, W_bond, b_bond, W_dmg, b_dmg, attn);
    gemm_bias_kernel<<<dim3(1024 / 64, 2048 / 64), blk, 0, stream>>>(
        attn, W_cproj, b_cproj, out, 2048, 1024, 1024);
}

// Round 2
// 408.839 us; speedup vs baseline: 2.4817x; 2.4817x over previous
//
#include <hip/hip_runtime.h>
#include <math.h>

// Problem constants: B=2, T=1024, C=1024, NH=16, HS=64, BD=16, HORIZON=64.

__device__ __forceinline__ float gelu_exact(float z) {
    return 0.5f * z * (1.0f + erff(z * 0.70710678118654752f));
}

// C = A @ B + bias ; A: MxK row-major, B: KxN row-major, C: MxN row-major.
// M,N multiples of 64; K multiple of 16. 256 threads, 64x64 tile, 4x4/thread.
__global__ __launch_bounds__(256) void gemm_bias_kernel(
    const float* __restrict__ A, const float* __restrict__ B,
    const float* __restrict__ bias, float* __restrict__ C,
    int M, int N, int K)
{
    __shared__ float As[16][68];
    __shared__ float Bs[16][64];
    const int tid = threadIdx.x;
    const int tx = tid & 15;
    const int ty = tid >> 4;
    const int rowbase = blockIdx.y * 64;
    const int colbase = blockIdx.x * 64;
    float acc[4][4] = {};

    for (int k0 = 0; k0 < K; k0 += 16) {
        {
            const int r  = tid >> 2;
            const int c4 = (tid & 3) << 2;
            const float4 a = *reinterpret_cast<const float4*>(
                A + (size_t)(rowbase + r) * K + k0 + c4);
            As[c4 + 0][r] = a.x; As[c4 + 1][r] = a.y;
            As[c4 + 2][r] = a.z; As[c4 + 3][r] = a.w;
        }
        {
            const int kr = tid >> 4;
            const int c4 = (tid & 15) << 2;
            *reinterpret_cast<float4*>(&Bs[kr][c4]) =
                *reinterpret_cast<const float4*>(
                    B + (size_t)(k0 + kr) * N + colbase + c4);
        }
        __syncthreads();
        #pragma unroll
        for (int k = 0; k < 16; ++k) {
            const float4 av = *reinterpret_cast<const float4*>(&As[k][ty * 4]);
            const float4 bv = *reinterpret_cast<const float4*>(&Bs[k][tx * 4]);
            const float a0[4] = {av.x, av.y, av.z, av.w};
            const float b0[4] = {bv.x, bv.y, bv.z, bv.w};
            #pragma unroll
            for (int i = 0; i < 4; ++i)
                #pragma unroll
                for (int jj = 0; jj < 4; ++jj)
                    acc[i][jj] += a0[i] * b0[jj];
        }
        __syncthreads();
    }
    #pragma unroll
    for (int i = 0; i < 4; ++i) {
        const int row = rowbase + ty * 4 + i;
        float* crow = C + (size_t)row * N + colbase;
        #pragma unroll
        for (int jj = 0; jj < 4; ++jj)
            crow[tx * 4 + jj] = acc[i][jj] + bias[colbase + tx * 4 + jj];
    }
}

// One wave per (b,h,t). Lane j computes the logit for window slot j, then a
// 64-lane softmax; weights written to ws. Loop nest is e-outer / d-inner so
// only strain[16] + scalars stay live (round-0 version spilled at 256 VGPR).
__global__ __launch_bounds__(256) void weights_kernel(
    const float* __restrict__ disp,   // (B*T, NH*BD=256)
    const float* __restrict__ rel,    // (64,16)
    const float* __restrict__ Wpos,   // (16,16)
    const float* __restrict__ Wfused, // (16,32)
    const float* __restrict__ bfused, // (32)
    const float* __restrict__ Wbond,  // (16)
    const float* __restrict__ bbond,  // (1)
    const float* __restrict__ Wdmg,   // (16)
    const float* __restrict__ bdmg,   // (1)
    float* __restrict__ wout)         // (B*NH*T, 64)
{
    __shared__ float posf[64][17];    // +1 pad: kills 16-stride bank conflict
    __shared__ float wf[16][32];
    __shared__ float sbias[32];
    __shared__ float wbd[16];
    __shared__ float wdm[16];
    const int tid = threadIdx.x;

    for (int i = tid; i < 512; i += 256) ((float*)wf)[i] = Wfused[i];
    if (tid < 32) sbias[tid] = bfused[tid];
    if (tid < 16) { wbd[tid] = Wbond[tid]; wdm[tid] = Wdmg[tid]; }
    for (int n = tid; n < 1024; n += 256) {
        const int j = n >> 4, e = n & 15;
        float s = 0.f;
        #pragma unroll
        for (int k = 0; k < 16; ++k) s += rel[j * 16 + k] * Wpos[k * 16 + e];
        posf[j][e] = s;
    }
    __syncthreads();
    const float bb = bbond[0];
    const float bd = bdmg[0];

    const int wave = tid >> 6;
    const int lane = tid & 63;
    const int gw = blockIdx.x * 4 + wave;   // (b*16+h)*1024 + t
    const int t  = gw & 1023;
    const int bh = gw >> 10;
    const int h  = bh & 15;
    const int b  = bh >> 4;

    const float* dt = disp + (size_t)(b * 1024 + t) * 256 + h * 16;
    const int j    = lane;
    const int tsrc = t + j - 63;
    const int rs   = b * 1024 + (tsrc < 0 ? 0 : tsrc);
    const float* dw = disp + (size_t)rs * 256 + h * 16;

    float strain[16];
    #pragma unroll
    for (int d = 0; d < 16; ++d) strain[d] = dw[d] - dt[d];

    float bond = bb, dmg = bd;
    #pragma unroll
    for (int e = 0; e < 16; ++e) {
        float bf = sbias[e];
        float df = sbias[16 + e];
        #pragma unroll
        for (int d = 0; d < 16; ++d) {
            bf += strain[d] * wf[d][e];
            df += strain[d] * wf[d][16 + e];
        }
        bond += gelu_exact(bf + posf[j][e]) * wbd[e];
        dmg  += gelu_exact(df) * wdm[e];
    }
    const float damage = 1.0f / (1.0f + __expf(-dmg));
    float logit = bond - 10.0f * damage;
    if (tsrc < 0) logit = -INFINITY;

    float m = logit;
    #pragma unroll
    for (int o = 32; o; o >>= 1) m = fmaxf(m, __shfl_xor(m, o));
    const float p = __expf(logit - m);
    float ssum = p;
    #pragma unroll
    for (int o = 32; o; o >>= 1) ssum += __shfl_xor(ssum, o);
    wout[(size_t)gw * 64 + lane] = p / ssum;
}

// One block per (b,h, 64-row t-tile). Stages the 127-row val window + 64x64
// weight tile in LDS; lane k accumulates channel k for 16 t-rows.
__global__ __launch_bounds__(256) void pv_kernel(
    const float* __restrict__ val,    // (B*T, C=1024)
    const float* __restrict__ w,      // (B*NH*T, 64)
    float* __restrict__ attn)         // (B*T, C=1024)
{
    __shared__ float Vs[127][64];     // row stride 64: 2-way bank alias = free
    __shared__ float Ws[64][65];
    const int tid = threadIdx.x;
    const int bh = blockIdx.x >> 4;   // 0..31
    const int t0 = (blockIdx.x & 15) * 64;
    const int b  = bh >> 4;
    const int h  = bh & 15;

    // Stage V window rows t0-63 .. t0+63 (clamped; masked slots get w=0).
    for (int n = tid * 4; n < 127 * 64; n += 256 * 4) {
        const int r = n >> 6;
        const int c = n & 63;
        int gr = t0 + r - 63;
        gr = gr < 0 ? 0 : gr;
        *reinterpret_cast<float4*>(&Vs[r][c]) =
            *reinterpret_cast<const float4*>(
                val + (size_t)(b * 1024 + gr) * 1024 + h * 64 + c);
    }
    for (int n = tid; n < 64 * 64; n += 256)
        Ws[n >> 6][n & 63] = w[((size_t)bh * 1024 + t0 + (n >> 6)) * 64 + (n & 63)];
    __syncthreads();

    const int k = tid & 63;
    const int tiBase = (tid >> 6) * 16;
    #pragma unroll
    for (int i = 0; i < 16; ++i) {
        const int ti = tiBase + i;
        float acc = 0.f;
        for (int jj = 0; jj < 64; ++jj)
            acc += Ws[ti][jj] * Vs[ti + jj][k];
        attn[(size_t)(b * 1024 + t0 + ti) * 1024 + h * 64 + k] = acc;
    }
}

extern "C" void kernel_launch(void* const* d_in, const int* in_sizes, int n_in,
                              void* d_out, int out_size, void* d_ws, size_t ws_size,
                              hipStream_t stream) {
    const float* x       = (const float*)d_in[0];
    const float* W_disp  = (const float*)d_in[1];
    const float* b_disp  = (const float*)d_in[2];
    const float* W_val   = (const float*)d_in[3];
    const float* b_val   = (const float*)d_in[4];
    const float* rel     = (const float*)d_in[5];
    const float* W_fused = (const float*)d_in[6];
    const float* b_fused = (const float*)d_in[7];
    const float* W_pos   = (const float*)d_in[8];
    const float* W_bond  = (const float*)d_in[9];
    const float* b_bond  = (const float*)d_in[10];
    const float* W_dmg   = (const float*)d_in[11];
    const float* b_dmg   = (const float*)d_in[12];
    const float* W_cproj = (const float*)d_in[13];
    const float* b_cproj = (const float*)d_in[14];
    float* out = (float*)d_out;

    // ws layout (fp32): disp 2048*256 | val 2048*1024 | attn 2048*1024 | w 32768*64
    float* disp = (float*)d_ws;
    float* val  = disp + 2048 * 256;
    float* attn = val  + 2048 * 1024;
    float* wbuf = attn + 2048 * 1024;

    dim3 blk(256);
    gemm_bias_kernel<<<dim3(256 / 64, 2048 / 64), blk, 0, stream>>>(
        x, W_disp, b_disp, disp, 2048, 256, 1024);
    gemm_bias_kernel<<<dim3(1024 / 64, 2048 / 64), blk, 0, stream>>>(
        x, W_val, b_val, val, 2048, 1024, 1024);
    weights_kernel<<<dim3(8192), blk, 0, stream>>>(
        disp, rel, W_pos, W_fused, b_fused, W_bond, b_bond, W_dmg, b_dmg, wbuf);
    pv_kernel<<<dim3(512), blk, 0, stream>>>(val, wbuf, attn);
    gemm_bias_kernel<<<dim3(1024 / 64, 2048 / 64), blk, 0, stream>>>(
        attn, W_cproj, b_cproj, out, 2048, 1024, 1024);
}

// Round 3
// 292.047 us; speedup vs baseline: 3.4742x; 1.3999x over previous
//
#include <hip/hip_runtime.h>
#include <math.h>

// Problem constants: B=2, T=1024, C=1024, NH=16, HS=64, BD=16, HORIZON=64.

// gelu tanh-form: gelu(z) ~= z * sigmoid(1.5957691*z*(1+0.044715 z^2)).
// Max abs error vs exact (erf) gelu ~1e-3 — well under the 6.7e-2 threshold.
__device__ __forceinline__ float gelu_fast(float z) {
    const float a = -1.5957691216057308f * z * fmaf(0.044715f, z * z, 1.0f);
    return z / (1.0f + __expf(a));
}

// C = A @ B + bias ; A: MxK row-major, B: KxN row-major, C: MxN row-major.
__global__ __launch_bounds__(256) void gemm_bias_kernel(
    const float* __restrict__ A, const float* __restrict__ B,
    const float* __restrict__ bias, float* __restrict__ C,
    int M, int N, int K)
{
    __shared__ float As[16][68];
    __shared__ float Bs[16][64];
    const int tid = threadIdx.x;
    const int tx = tid & 15;
    const int ty = tid >> 4;
    const int rowbase = blockIdx.y * 64;
    const int colbase = blockIdx.x * 64;
    float acc[4][4] = {};

    for (int k0 = 0; k0 < K; k0 += 16) {
        {
            const int r  = tid >> 2;
            const int c4 = (tid & 3) << 2;
            const float4 a = *reinterpret_cast<const float4*>(
                A + (size_t)(rowbase + r) * K + k0 + c4);
            As[c4 + 0][r] = a.x; As[c4 + 1][r] = a.y;
            As[c4 + 2][r] = a.z; As[c4 + 3][r] = a.w;
        }
        {
            const int kr = tid >> 4;
            const int c4 = (tid & 15) << 2;
            *reinterpret_cast<float4*>(&Bs[kr][c4]) =
                *reinterpret_cast<const float4*>(
                    B + (size_t)(k0 + kr) * N + colbase + c4);
        }
        __syncthreads();
        #pragma unroll
        for (int k = 0; k < 16; ++k) {
            const float4 av = *reinterpret_cast<const float4*>(&As[k][ty * 4]);
            const float4 bv = *reinterpret_cast<const float4*>(&Bs[k][tx * 4]);
            const float a0[4] = {av.x, av.y, av.z, av.w};
            const float b0[4] = {bv.x, bv.y, bv.z, bv.w};
            #pragma unroll
            for (int i = 0; i < 4; ++i)
                #pragma unroll
                for (int jj = 0; jj < 4; ++jj)
                    acc[i][jj] += a0[i] * b0[jj];
        }
        __syncthreads();
    }
    #pragma unroll
    for (int i = 0; i < 4; ++i) {
        const int row = rowbase + ty * 4 + i;
        float* crow = C + (size_t)row * N + colbase;
        #pragma unroll
        for (int jj = 0; jj < 4; ++jj)
            crow[tx * 4 + jj] = acc[i][jj] + bias[colbase + tx * 4 + jj];
    }
}

// Folds W_disp@W_fused -> W_comb (1024,512); also b_comb and posf=rel@W_pos.
__global__ __launch_bounds__(256) void fold_kernel(
    const float* __restrict__ W_disp,  // (1024,256)
    const float* __restrict__ b_disp,  // (256)
    const float* __restrict__ W_fused, // (16,32)
    const float* __restrict__ rel,     // (64,16)
    const float* __restrict__ Wpos,    // (16,16)
    float* __restrict__ W_comb,        // (1024,512)
    float* __restrict__ b_comb,        // (512)
    float* __restrict__ posf)          // (64,16)
{
    const int bid = blockIdx.x, tid = threadIdx.x;
    if (bid < 2048) {
        const int idx = bid * 256 + tid;   // 0..524287
        const int r = idx >> 9;
        const int cc = idx & 511;
        const int h = cc >> 5, e = cc & 31;
        float s = 0.f;
        #pragma unroll
        for (int d = 0; d < 16; ++d)
            s += W_disp[r * 256 + h * 16 + d] * W_fused[d * 32 + e];
        W_comb[idx] = s;
    } else if (bid == 2048) {
        for (int n = tid; n < 1024; n += 256) {
            const int j = n >> 4, e = n & 15;
            float s = 0.f;
            #pragma unroll
            for (int k = 0; k < 16; ++k) s += rel[j * 16 + k] * Wpos[k * 16 + e];
            posf[n] = s;
        }
    } else {
        for (int n = tid; n < 512; n += 256) {
            const int h = n >> 5, e = n & 31;
            float s = 0.f;
            #pragma unroll
            for (int d = 0; d < 16; ++d)
                s += b_disp[h * 16 + d] * W_fused[d * 32 + e];
            b_comb[n] = s;
        }
    }
}

// One wave per (b,h,t). fused = dproj[w]-dproj[t]+b_fused (b_comb cancels in
// the difference), then the gelu heads + softmax. MLP GEMM is gone.
__global__ __launch_bounds__(256) void weights_kernel(
    const float* __restrict__ dproj,  // (B*T, 512)
    const float* __restrict__ posf_g, // (64,16)
    const float* __restrict__ bfused, // (32)
    const float* __restrict__ Wbond,  // (16)
    const float* __restrict__ bbond,  // (1)
    const float* __restrict__ Wdmg,   // (16)
    const float* __restrict__ bdmg,   // (1)
    float* __restrict__ wout)         // (B*NH*T, 64)
{
    __shared__ float posf[64][17];
    __shared__ float sb[32];
    __shared__ float wbd[16];
    __shared__ float wdm[16];
    const int tid = threadIdx.x;

    if (tid < 32) sb[tid] = bfused[tid];
    if (tid < 16) { wbd[tid] = Wbond[tid]; wdm[tid] = Wdmg[tid]; }
    for (int n = tid; n < 1024; n += 256) posf[n >> 4][n & 15] = posf_g[n];
    __syncthreads();
    const float bb = bbond[0];
    const float bd = bdmg[0];

    const int wave = tid >> 6;
    const int lane = tid & 63;
    const int gw = blockIdx.x * 4 + wave;   // (b*16+h)*1024 + t
    const int t  = gw & 1023;
    const int bh = gw >> 10;
    const int h  = bh & 15;
    const int b  = bh >> 4;

    const int tsrc = t + lane - 63;
    const int rs   = b * 1024 + (tsrc < 0 ? 0 : tsrc);
    const float* pw = dproj + (size_t)rs * 512 + h * 32;
    const float* pt = dproj + (size_t)(b * 1024 + t) * 512 + h * 32;

    float fused[32];
    #pragma unroll
    for (int q = 0; q < 8; ++q) {
        const float4 a = *reinterpret_cast<const float4*>(pw + q * 4);
        const float4 c = *reinterpret_cast<const float4*>(pt + q * 4);
        fused[q * 4 + 0] = a.x - c.x + sb[q * 4 + 0];
        fused[q * 4 + 1] = a.y - c.y + sb[q * 4 + 1];
        fused[q * 4 + 2] = a.z - c.z + sb[q * 4 + 2];
        fused[q * 4 + 3] = a.w - c.w + sb[q * 4 + 3];
    }

    float bond = bb, dmg = bd;
    #pragma unroll
    for (int e = 0; e < 16; ++e) {
        bond += gelu_fast(fused[e] + posf[lane][e]) * wbd[e];
        dmg  += gelu_fast(fused[16 + e]) * wdm[e];
    }
    const float damage = 1.0f / (1.0f + __expf(-dmg));
    float logit = bond - 10.0f * damage;
    if (tsrc < 0) logit = -INFINITY;

    float m = logit;
    #pragma unroll
    for (int o = 32; o; o >>= 1) m = fmaxf(m, __shfl_xor(m, o));
    const float p = __expf(logit - m);
    float ssum = p;
    #pragma unroll
    for (int o = 32; o; o >>= 1) ssum += __shfl_xor(ssum, o);
    wout[(size_t)gw * 64 + lane] = p / ssum;
}

// One block per (b,h, 64-row t-tile). Stages the 127-row val window + 64x64
// weight tile in LDS; lane k accumulates channel k for 16 t-rows.
__global__ __launch_bounds__(256) void pv_kernel(
    const float* __restrict__ val,    // (B*T, C=1024)
    const float* __restrict__ w,      // (B*NH*T, 64)
    float* __restrict__ attn)         // (B*T, C=1024)
{
    __shared__ float Vs[127][64];
    __shared__ float Ws[64][65];
    const int tid = threadIdx.x;
    const int bh = blockIdx.x >> 4;
    const int t0 = (blockIdx.x & 15) * 64;
    const int b  = bh >> 4;
    const int h  = bh & 15;

    for (int n = tid * 4; n < 127 * 64; n += 256 * 4) {
        const int r = n >> 6;
        const int c = n & 63;
        int gr = t0 + r - 63;
        gr = gr < 0 ? 0 : gr;
        *reinterpret_cast<float4*>(&Vs[r][c]) =
            *reinterpret_cast<const float4*>(
                val + (size_t)(b * 1024 + gr) * 1024 + h * 64 + c);
    }
    for (int n = tid; n < 64 * 64; n += 256)
        Ws[n >> 6][n & 63] = w[((size_t)bh * 1024 + t0 + (n >> 6)) * 64 + (n & 63)];
    __syncthreads();

    const int k = tid & 63;
    const int tiBase = (tid >> 6) * 16;
    #pragma unroll
    for (int i = 0; i < 16; ++i) {
        const int ti = tiBase + i;
        float acc = 0.f;
        for (int jj = 0; jj < 64; ++jj)
            acc += Ws[ti][jj] * Vs[ti + jj][k];
        attn[(size_t)(b * 1024 + t0 + ti) * 1024 + h * 64 + k] = acc;
    }
}

extern "C" void kernel_launch(void* const* d_in, const int* in_sizes, int n_in,
                              void* d_out, int out_size, void* d_ws, size_t ws_size,
                              hipStream_t stream) {
    const float* x       = (const float*)d_in[0];
    const float* W_disp  = (const float*)d_in[1];
    const float* b_disp  = (const float*)d_in[2];
    const float* W_val   = (const float*)d_in[3];
    const float* b_val   = (const float*)d_in[4];
    const float* rel     = (const float*)d_in[5];
    const float* W_fused = (const float*)d_in[6];
    const float* b_fused = (const float*)d_in[7];
    const float* W_pos   = (const float*)d_in[8];
    const float* W_bond  = (const float*)d_in[9];
    const float* b_bond  = (const float*)d_in[10];
    const float* W_dmg   = (const float*)d_in[11];
    const float* b_dmg   = (const float*)d_in[12];
    const float* W_cproj = (const float*)d_in[13];
    const float* b_cproj = (const float*)d_in[14];
    float* out = (float*)d_out;

    // ws (fp32): dproj 2048*512 | val 2048*1024 | attn 2048*1024 (W_comb
    // aliases its first 512K floats — dead before pv writes attn) |
    // wbuf 32768*64 | b_comb 512 | posf 1024
    float* dproj  = (float*)d_ws;
    float* val    = dproj + 2048 * 512;
    float* attn   = val + 2048 * 1024;
    float* W_comb = attn;                 // alias: consumed before attn is written
    float* wbuf   = attn + 2048 * 1024;
    float* b_comb = wbuf + 32768 * 64;
    float* posf   = b_comb + 512;

    dim3 blk(256);
    fold_kernel<<<dim3(2050), blk, 0, stream>>>(
        W_disp, b_disp, W_fused, rel, W_pos, W_comb, b_comb, posf);
    gemm_bias_kernel<<<dim3(512 / 64, 2048 / 64), blk, 0, stream>>>(
        x, W_comb, b_comb, dproj, 2048, 512, 1024);
    gemm_bias_kernel<<<dim3(1024 / 64, 2048 / 64), blk, 0, stream>>>(
        x, W_val, b_val, val, 2048, 1024, 1024);
    weights_kernel<<<dim3(8192), blk, 0, stream>>>(
        dproj, posf, b_fused, W_bond, b_bond, W_dmg, b_dmg, wbuf);
    pv_kernel<<<dim3(512), blk, 0, stream>>>(val, wbuf, attn);
    gemm_bias_kernel<<<dim3(1024 / 64, 2048 / 64), blk, 0, stream>>>(
        attn, W_cproj, b_cproj, out, 2048, 1024, 1024);
}

// Round 4
// 145.065 us; speedup vs baseline: 6.9942x; 2.0132x over previous
//
#include <hip/hip_runtime.h>
#include <math.h>

// Problem constants: B=2, T=1024, C=1024, NH=16, HS=64, BD=16, HORIZON=64.

typedef __attribute__((ext_vector_type(4))) float f32x4;
typedef __attribute__((ext_vector_type(8))) __bf16 bf16x8;

__device__ __forceinline__ ushort f2bf(float f) {
    union { float f; unsigned u; } v; v.f = f;
    const unsigned r = v.u + 0x7fffu + ((v.u >> 16) & 1u);   // RNE
    return (ushort)(r >> 16);
}

// gelu tanh-form: max abs err ~1e-3, fine vs 6.7e-2 threshold.
__device__ __forceinline__ float gelu_fast(float z) {
    const float a = -1.5957691216057308f * z * fmaf(0.044715f, z * z, 1.0f);
    return z / (1.0f + __expf(a));
}

// ---------------- bf16 MFMA GEMM ----------------
// C(M,N) = A(M,K)bf16 @ B(K,N) + bias, with B given pre-transposed Bt(N,K)bf16.
// 128x64 tile, BK=64, 256 threads (4 waves, 2x2), 16x16x32 MFMA.
// LDS staged via global_load_lds width=16; XOR-swizzle (T2) applied on the
// global SOURCE and on the ds_read addr (both-sides, rule #21).
__global__ __launch_bounds__(256) void gemm_bf16_kernel(
    const ushort* __restrict__ A,    // (M,K) bf16
    const ushort* __restrict__ Bt,   // (N,K) bf16
    const float* __restrict__ bias,  // (N) — ignored if hasBias==0
    float* __restrict__ C,           // (M,N) fp32
    int M, int N, int K, int hasBias)
{
    __shared__ ushort As[128 * 64];  // [row][k] swizzled, 16 KB
    __shared__ ushort Bs[64 * 64];   // [n][k]   swizzled,  8 KB
    const int tid  = threadIdx.x;
    const int wave = tid >> 6;
    const int lane = tid & 63;
    const int rowbase = blockIdx.y * 128;
    const int colbase = blockIdx.x * 64;
    const int wr = wave >> 1;        // wave tile: 64 rows x 32 cols
    const int wc = wave & 1;

    f32x4 acc[4][2] = {};

    for (int k0 = 0; k0 < K; k0 += 64) {
        // stage A: 1024 chunks of 16B, 4 per lane
        #pragma unroll
        for (int i = 0; i < 4; ++i) {
            const int p   = (i * 4 + wave) * 64 + lane;
            const int row = p >> 3;
            const int kc  = (p & 7) ^ (row & 7);          // pre-swizzled source
            const ushort* src = A + (size_t)(rowbase + row) * K + k0 + kc * 8;
            __builtin_amdgcn_global_load_lds(
                (const __attribute__((address_space(1))) void*)src,
                (__attribute__((address_space(3))) void*)(As + (size_t)p * 8),
                16, 0, 0);
        }
        // stage B: 512 chunks, 2 per lane
        #pragma unroll
        for (int i = 0; i < 2; ++i) {
            const int p   = (i * 4 + wave) * 64 + lane;
            const int row = p >> 3;
            const int kc  = (p & 7) ^ (row & 7);
            const ushort* src = Bt + (size_t)(colbase + row) * K + k0 + kc * 8;
            __builtin_amdgcn_global_load_lds(
                (const __attribute__((address_space(1))) void*)src,
                (__attribute__((address_space(3))) void*)(Bs + (size_t)p * 8),
                16, 0, 0);
        }
        __syncthreads();

        #pragma unroll
        for (int kk = 0; kk < 2; ++kk) {
            const int kb = kk * 32 + (lane >> 4) * 8;     // element k base
            bf16x8 a[4], b[2];
            #pragma unroll
            for (int ni = 0; ni < 2; ++ni) {
                const int n = wc * 32 + ni * 16 + (lane & 15);
                int off = n * 128 + kb * 2;
                off ^= (n & 7) << 4;                       // T2 read swizzle
                b[ni] = *(const bf16x8*)((const char*)Bs + off);
            }
            #pragma unroll
            for (int mi = 0; mi < 4; ++mi) {
                const int r = wr * 64 + mi * 16 + (lane & 15);
                int off = r * 128 + kb * 2;
                off ^= (r & 7) << 4;
                a[mi] = *(const bf16x8*)((const char*)As + off);
            }
            #pragma unroll
            for (int mi = 0; mi < 4; ++mi)
                #pragma unroll
                for (int ni = 0; ni < 2; ++ni)
                    acc[mi][ni] = __builtin_amdgcn_mfma_f32_16x16x32_bf16(
                        a[mi], b[ni], acc[mi][ni], 0, 0, 0);
        }
        __syncthreads();
    }

    #pragma unroll
    for (int mi = 0; mi < 4; ++mi)
        #pragma unroll
        for (int ni = 0; ni < 2; ++ni) {
            const int col = colbase + wc * 32 + ni * 16 + (lane & 15);
            const float bv = hasBias ? bias[col] : 0.0f;
            #pragma unroll
            for (int r = 0; r < 4; ++r) {
                const int row = rowbase + wr * 64 + mi * 16 + (lane >> 4) * 4 + r;
                C[(size_t)row * N + col] = acc[mi][ni][r] + bv;
            }
        }
}

// fp32 -> bf16 cast, 4 elems/thread.
__global__ __launch_bounds__(256) void cast_kernel(
    const float* __restrict__ in, ushort* __restrict__ outp, int nvec4)
{
    const int idx = blockIdx.x * 256 + threadIdx.x;
    if (idx < nvec4) {
        const float4 v = reinterpret_cast<const float4*>(in)[idx];
        ushort4 o; o.x = f2bf(v.x); o.y = f2bf(v.y); o.z = f2bf(v.z); o.w = f2bf(v.w);
        reinterpret_cast<ushort4*>(outp)[idx] = o;
    }
}

// W (K,N) fp32 row-major -> Wt (N,K) bf16 row-major. 64x64 LDS transpose.
__global__ __launch_bounds__(256) void tcast_kernel(
    const float* __restrict__ W, ushort* __restrict__ Wt, int K, int N)
{
    __shared__ float tile[64][65];
    const int tid = threadIdx.x;
    const int n0 = blockIdx.x * 64;
    const int k0 = blockIdx.y * 64;
    #pragma unroll
    for (int i = 0; i < 4; ++i) {
        const int idx = tid + i * 256;
        const int r = idx >> 4;
        const int c = (idx & 15) << 2;
        const float4 v = *reinterpret_cast<const float4*>(
            W + (size_t)(k0 + r) * N + n0 + c);
        tile[r][c] = v.x; tile[r][c + 1] = v.y; tile[r][c + 2] = v.z; tile[r][c + 3] = v.w;
    }
    __syncthreads();
    #pragma unroll
    for (int i = 0; i < 4; ++i) {
        const int idx = tid + i * 256;
        const int n = idx >> 4;
        const int c = (idx & 15) << 2;
        ushort4 o;
        o.x = f2bf(tile[c][n]);     o.y = f2bf(tile[c + 1][n]);
        o.z = f2bf(tile[c + 2][n]); o.w = f2bf(tile[c + 3][n]);
        *reinterpret_cast<ushort4*>(Wt + (size_t)(n0 + n) * K + k0 + c) = o;
    }
}

// Folds W_disp@W_fused -> W_combT (512,1024) bf16 (transposed for the GEMM);
// also posf = rel@W_pos. (b_comb cancels in the strain difference — dropped.)
__global__ __launch_bounds__(256) void fold_kernel(
    const float* __restrict__ W_disp,  // (1024,256)
    const float* __restrict__ W_fused, // (16,32)
    const float* __restrict__ rel,     // (64,16)
    const float* __restrict__ Wpos,    // (16,16)
    ushort* __restrict__ W_combT,      // (512,1024) bf16 [cc][r]
    float* __restrict__ posf)          // (64,16)
{
    __shared__ float wfs[512];
    const int bid = blockIdx.x, tid = threadIdx.x;
    if (bid < 2048) {
        for (int i = tid; i < 512; i += 256) wfs[i] = W_fused[i];
        __syncthreads();
        const int idx = bid * 256 + tid;   // cc*1024 + r
        const int cc = idx >> 10;
        const int r  = idx & 1023;
        const int h = cc >> 5, e = cc & 31;
        const float* wd = W_disp + r * 256 + h * 16;
        float s = 0.f;
        #pragma unroll
        for (int d = 0; d < 16; ++d) s += wd[d] * wfs[d * 32 + e];
        W_combT[idx] = f2bf(s);
    } else {
        for (int n = tid; n < 1024; n += 256) {
            const int j = n >> 4, e = n & 15;
            float s = 0.f;
            #pragma unroll
            for (int k = 0; k < 16; ++k) s += rel[j * 16 + k] * Wpos[k * 16 + e];
            posf[n] = s;
        }
    }
}

// One wave per (b,h,t): fused = dproj[w]-dproj[t]+b_fused, gelu heads, softmax.
__global__ __launch_bounds__(256) void weights_kernel(
    const float* __restrict__ dproj,  // (B*T, 512)
    const float* __restrict__ posf_g, // (64,16)
    const float* __restrict__ bfused, // (32)
    const float* __restrict__ Wbond,  // (16)
    const float* __restrict__ bbond,  // (1)
    const float* __restrict__ Wdmg,   // (16)
    const float* __restrict__ bdmg,   // (1)
    float* __restrict__ wout)         // (B*NH*T, 64)
{
    __shared__ float posf[64][17];
    __shared__ float sb[32];
    __shared__ float wbd[16];
    __shared__ float wdm[16];
    const int tid = threadIdx.x;

    if (tid < 32) sb[tid] = bfused[tid];
    if (tid < 16) { wbd[tid] = Wbond[tid]; wdm[tid] = Wdmg[tid]; }
    for (int n = tid; n < 1024; n += 256) posf[n >> 4][n & 15] = posf_g[n];
    __syncthreads();
    const float bb = bbond[0];
    const float bd = bdmg[0];

    const int wave = tid >> 6;
    const int lane = tid & 63;
    const int gw = blockIdx.x * 4 + wave;
    const int t  = gw & 1023;
    const int bh = gw >> 10;
    const int h  = bh & 15;
    const int b  = bh >> 4;

    const int tsrc = t + lane - 63;
    const int rs   = b * 1024 + (tsrc < 0 ? 0 : tsrc);
    const float* pw = dproj + (size_t)rs * 512 + h * 32;
    const float* pt = dproj + (size_t)(b * 1024 + t) * 512 + h * 32;

    float fused[32];
    #pragma unroll
    for (int q = 0; q < 8; ++q) {
        const float4 a = *reinterpret_cast<const float4*>(pw + q * 4);
        const float4 c = *reinterpret_cast<const float4*>(pt + q * 4);
        fused[q * 4 + 0] = a.x - c.x + sb[q * 4 + 0];
        fused[q * 4 + 1] = a.y - c.y + sb[q * 4 + 1];
        fused[q * 4 + 2] = a.z - c.z + sb[q * 4 + 2];
        fused[q * 4 + 3] = a.w - c.w + sb[q * 4 + 3];
    }

    float bond = bb, dmg = bd;
    #pragma unroll
    for (int e = 0; e < 16; ++e) {
        bond += gelu_fast(fused[e] + posf[lane][e]) * wbd[e];
        dmg  += gelu_fast(fused[16 + e]) * wdm[e];
    }
    const float damage = 1.0f / (1.0f + __expf(-dmg));
    float logit = bond - 10.0f * damage;
    if (tsrc < 0) logit = -INFINITY;

    float m = logit;
    #pragma unroll
    for (int o = 32; o; o >>= 1) m = fmaxf(m, __shfl_xor(m, o));
    const float p = __expf(logit - m);
    float ssum = p;
    #pragma unroll
    for (int o = 32; o; o >>= 1) ssum += __shfl_xor(ssum, o);
    wout[(size_t)gw * 64 + lane] = p / ssum;
}

// One block per (b,h,64-row t-tile); writes attn directly as bf16 for cproj.
__global__ __launch_bounds__(256) void pv_kernel(
    const float* __restrict__ val,    // (B*T, C=1024)
    const float* __restrict__ w,      // (B*NH*T, 64)
    ushort* __restrict__ attnb)       // (B*T, C=1024) bf16
{
    __shared__ float Vs[127][64];
    __shared__ float Ws[64][65];
    const int tid = threadIdx.x;
    const int bh = blockIdx.x >> 4;
    const int t0 = (blockIdx.x & 15) * 64;
    const int b  = bh >> 4;
    const int h  = bh & 15;

    for (int n = tid * 4; n < 127 * 64; n += 256 * 4) {
        const int r = n >> 6;
        const int c = n & 63;
        int gr = t0 + r - 63;
        gr = gr < 0 ? 0 : gr;
        *reinterpret_cast<float4*>(&Vs[r][c]) =
            *reinterpret_cast<const float4*>(
                val + (size_t)(b * 1024 + gr) * 1024 + h * 64 + c);
    }
    for (int n = tid; n < 64 * 64; n += 256)
        Ws[n >> 6][n & 63] = w[((size_t)bh * 1024 + t0 + (n >> 6)) * 64 + (n & 63)];
    __syncthreads();

    const int k = tid & 63;
    const int tiBase = (tid >> 6) * 16;
    #pragma unroll
    for (int i = 0; i < 16; ++i) {
        const int ti = tiBase + i;
        float acc = 0.f;
        for (int jj = 0; jj < 64; ++jj)
            acc += Ws[ti][jj] * Vs[ti + jj][k];
        attnb[(size_t)(b * 1024 + t0 + ti) * 1024 + h * 64 + k] = f2bf(acc);
    }
}

extern "C" void kernel_launch(void* const* d_in, const int* in_sizes, int n_in,
                              void* d_out, int out_size, void* d_ws, size_t ws_size,
                              hipStream_t stream) {
    const float* x       = (const float*)d_in[0];
    const float* W_disp  = (const float*)d_in[1];
    const float* W_val   = (const float*)d_in[3];
    const float* b_val   = (const float*)d_in[4];
    const float* rel     = (const float*)d_in[5];
    const float* W_fused = (const float*)d_in[6];
    const float* b_fused = (const float*)d_in[7];
    const float* W_pos   = (const float*)d_in[8];
    const float* W_bond  = (const float*)d_in[9];
    const float* b_bond  = (const float*)d_in[10];
    const float* W_dmg   = (const float*)d_in[11];
    const float* b_dmg   = (const float*)d_in[12];
    const float* W_cproj = (const float*)d_in[13];
    const float* b_cproj = (const float*)d_in[14];
    float* out = (float*)d_out;

    // ws: xb 4MB | WvT 2MB | WcT 2MB | WcombT 1MB | dproj 4MB (aliased by
    // attnb after weights_kernel) | val 8MB | wbuf 8MB | posf 4KB  = ~29MB
    ushort* xb      = (ushort*)d_ws;
    ushort* WvT     = xb + 2048 * 1024;
    ushort* WcT     = WvT + 1024 * 1024;
    ushort* WcombT  = WcT + 1024 * 1024;
    float*  dproj   = (float*)(WcombT + 512 * 1024);
    ushort* attnb   = (ushort*)dproj;            // alias: dproj dead before pv
    float*  val     = dproj + 2048 * 512;
    float*  wbuf    = val + 2048 * 1024;
    float*  posf    = wbuf + 32768 * 64;

    dim3 blk(256);
    fold_kernel<<<dim3(2049), blk, 0, stream>>>(
        W_disp, W_fused, rel, W_pos, WcombT, posf);
    cast_kernel<<<dim3(2048), blk, 0, stream>>>(x, xb, 2048 * 1024 / 4);
    tcast_kernel<<<dim3(16, 16), blk, 0, stream>>>(W_val, WvT, 1024, 1024);
    tcast_kernel<<<dim3(16, 16), blk, 0, stream>>>(W_cproj, WcT, 1024, 1024);

    gemm_bf16_kernel<<<dim3(512 / 64, 2048 / 128), blk, 0, stream>>>(
        xb, WcombT, nullptr, dproj, 2048, 512, 1024, 0);
    gemm_bf16_kernel<<<dim3(1024 / 64, 2048 / 128), blk, 0, stream>>>(
        xb, WvT, b_val, val, 2048, 1024, 1024, 1);
    weights_kernel<<<dim3(8192), blk, 0, stream>>>(
        dproj, posf, b_fused, W_bond, b_bond, W_dmg, b_dmg, wbuf);
    pv_kernel<<<dim3(512), blk, 0, stream>>>(val, wbuf, attnb);
    gemm_bf16_kernel<<<dim3(1024 / 64, 2048 / 128), blk, 0, stream>>>(
        attnb, WcT, b_cproj, out, 2048, 1024, 1024, 1);
}

// Round 5
// 115.917 us; speedup vs baseline: 8.7530x; 1.2515x over previous
//
#include <hip/hip_runtime.h>
#include <math.h>

// Problem constants: B=2, T=1024, C=1024, NH=16, HS=64, BD=16, HORIZON=64.

typedef __attribute__((ext_vector_type(4))) float f32x4;
typedef __attribute__((ext_vector_type(8))) __bf16 bf16x8;

__device__ __forceinline__ ushort f2bf(float f) {
    union { float f; unsigned u; } v; v.f = f;
    const unsigned r = v.u + 0x7fffu + ((v.u >> 16) & 1u);   // RNE
    return (ushort)(r >> 16);
}

// gelu tanh-form: max abs err ~1e-3, fine vs 6.7e-2 threshold.
__device__ __forceinline__ float gelu_fast(float z) {
    const float a = -1.5957691216057308f * z * fmaf(0.044715f, z * z, 1.0f);
    return z * __builtin_amdgcn_rcpf(1.0f + __expf(a));
}

// ---------------- bf16 MFMA GEMM ----------------
// C(M,N) = A(M,K)bf16 @ B(K,N) + bias, B pre-transposed Bt(N,K)bf16.
// 64x64 tile, BK=64, 4 waves (2x2 quadrants of 32x32), 16x16x32 MFMA.
// global_load_lds width=16 staging; T2 XOR swizzle both-sides (rule #21).
__global__ __launch_bounds__(256) void gemm_bf16_kernel(
    const ushort* __restrict__ A,    // (M,K) bf16
    const ushort* __restrict__ Bt,   // (N,K) bf16
    const float* __restrict__ bias,  // (N) — ignored if hasBias==0
    float* __restrict__ C,           // (M,N) fp32
    int M, int N, int K, int hasBias)
{
    __shared__ ushort As[64 * 64];   // [row][k] swizzled, 8 KB
    __shared__ ushort Bs[64 * 64];   // [n][k]   swizzled, 8 KB
    const int tid  = threadIdx.x;
    const int wave = tid >> 6;
    const int lane = tid & 63;
    const int rowbase = blockIdx.y * 64;
    const int colbase = blockIdx.x * 64;
    const int wr = wave >> 1;        // 32-row quadrant
    const int wc = wave & 1;         // 32-col quadrant

    f32x4 acc[2][2] = {};

    for (int k0 = 0; k0 < K; k0 += 64) {
        #pragma unroll
        for (int i = 0; i < 2; ++i) {
            const int p   = (i * 4 + wave) * 64 + lane;   // 0..511
            const int row = p >> 3;
            const int kc  = (p & 7) ^ (row & 7);          // pre-swizzled source
            const ushort* srcA = A + (size_t)(rowbase + row) * K + k0 + kc * 8;
            __builtin_amdgcn_global_load_lds(
                (const __attribute__((address_space(1))) void*)srcA,
                (__attribute__((address_space(3))) void*)(As + (size_t)p * 8),
                16, 0, 0);
            const ushort* srcB = Bt + (size_t)(colbase + row) * K + k0 + kc * 8;
            __builtin_amdgcn_global_load_lds(
                (const __attribute__((address_space(1))) void*)srcB,
                (__attribute__((address_space(3))) void*)(Bs + (size_t)p * 8),
                16, 0, 0);
        }
        __syncthreads();

        #pragma unroll
        for (int kk = 0; kk < 2; ++kk) {
            const int kb = kk * 32 + (lane >> 4) * 8;
            bf16x8 a[2], b[2];
            #pragma unroll
            for (int ni = 0; ni < 2; ++ni) {
                const int n = wc * 32 + ni * 16 + (lane & 15);
                int off = n * 128 + kb * 2;
                off ^= (n & 7) << 4;                       // T2 read swizzle
                b[ni] = *(const bf16x8*)((const char*)Bs + off);
            }
            #pragma unroll
            for (int mi = 0; mi < 2; ++mi) {
                const int r = wr * 32 + mi * 16 + (lane & 15);
                int off = r * 128 + kb * 2;
                off ^= (r & 7) << 4;
                a[mi] = *(const bf16x8*)((const char*)As + off);
            }
            #pragma unroll
            for (int mi = 0; mi < 2; ++mi)
                #pragma unroll
                for (int ni = 0; ni < 2; ++ni)
                    acc[mi][ni] = __builtin_amdgcn_mfma_f32_16x16x32_bf16(
                        a[mi], b[ni], acc[mi][ni], 0, 0, 0);
        }
        __syncthreads();
    }

    #pragma unroll
    for (int mi = 0; mi < 2; ++mi)
        #pragma unroll
        for (int ni = 0; ni < 2; ++ni) {
            const int col = colbase + wc * 32 + ni * 16 + (lane & 15);
            const float bv = hasBias ? bias[col] : 0.0f;
            #pragma unroll
            for (int r = 0; r < 4; ++r) {
                const int row = rowbase + wr * 32 + mi * 16 + (lane >> 4) * 4 + r;
                C[(size_t)row * N + col] = acc[mi][ni][r] + bv;
            }
        }
}

// fp32 -> bf16 cast, 4 elems/thread.
__global__ __launch_bounds__(256) void cast_kernel(
    const float* __restrict__ in, ushort* __restrict__ outp, int nvec4)
{
    const int idx = blockIdx.x * 256 + threadIdx.x;
    if (idx < nvec4) {
        const float4 v = reinterpret_cast<const float4*>(in)[idx];
        ushort4 o; o.x = f2bf(v.x); o.y = f2bf(v.y); o.z = f2bf(v.z); o.w = f2bf(v.w);
        reinterpret_cast<ushort4*>(outp)[idx] = o;
    }
}

// W (K,N) fp32 row-major -> Wt (N,K) bf16 row-major. 64x64 LDS transpose.
__global__ __launch_bounds__(256) void tcast_kernel(
    const float* __restrict__ W, ushort* __restrict__ Wt, int K, int N)
{
    __shared__ float tile[64][65];
    const int tid = threadIdx.x;
    const int n0 = blockIdx.x * 64;
    const int k0 = blockIdx.y * 64;
    #pragma unroll
    for (int i = 0; i < 4; ++i) {
        const int idx = tid + i * 256;
        const int r = idx >> 4;
        const int c = (idx & 15) << 2;
        const float4 v = *reinterpret_cast<const float4*>(
            W + (size_t)(k0 + r) * N + n0 + c);
        tile[r][c] = v.x; tile[r][c + 1] = v.y; tile[r][c + 2] = v.z; tile[r][c + 3] = v.w;
    }
    __syncthreads();
    #pragma unroll
    for (int i = 0; i < 4; ++i) {
        const int idx = tid + i * 256;
        const int n = idx >> 4;
        const int c = (idx & 15) << 2;
        ushort4 o;
        o.x = f2bf(tile[c][n]);     o.y = f2bf(tile[c + 1][n]);
        o.z = f2bf(tile[c + 2][n]); o.w = f2bf(tile[c + 3][n]);
        *reinterpret_cast<ushort4*>(Wt + (size_t)(n0 + n) * K + k0 + c) = o;
    }
}

// Folds W_disp@W_fused -> W_combT (512,1024) bf16; posf = rel@W_pos.
__global__ __launch_bounds__(256) void fold_kernel(
    const float* __restrict__ W_disp,  // (1024,256)
    const float* __restrict__ W_fused, // (16,32)
    const float* __restrict__ rel,     // (64,16)
    const float* __restrict__ Wpos,    // (16,16)
    ushort* __restrict__ W_combT,      // (512,1024) bf16 [cc][r]
    float* __restrict__ posf)          // (64,16)
{
    __shared__ float wfs[512];
    const int bid = blockIdx.x, tid = threadIdx.x;
    if (bid < 2048) {
        for (int i = tid; i < 512; i += 256) wfs[i] = W_fused[i];
        __syncthreads();
        const int idx = bid * 256 + tid;   // cc*1024 + r
        const int cc = idx >> 10;
        const int r  = idx & 1023;
        const int h = cc >> 5, e = cc & 31;
        const float* wd = W_disp + r * 256 + h * 16;
        float s = 0.f;
        #pragma unroll
        for (int d = 0; d < 16; ++d) s += wd[d] * wfs[d * 32 + e];
        W_combT[idx] = f2bf(s);
    } else {
        for (int n = tid; n < 1024; n += 256) {
            const int j = n >> 4, e = n & 15;
            float s = 0.f;
            #pragma unroll
            for (int k = 0; k < 16; ++k) s += rel[j * 16 + k] * Wpos[k * 16 + e];
            posf[n] = s;
        }
    }
}

// Block = one (b,h) x 4 consecutive t (one wave per t). The 67-row dproj
// window for this head is staged in LDS transposed as float2[16][68]
// (coalesced global reads; ds_read_b64 at 8B lane stride = conflict-free;
// the t-row read is a wave-uniform broadcast). posf lives in 16 regs/lane.
__global__ __launch_bounds__(256) void weights_kernel(
    const float* __restrict__ dproj,  // (B*T, 512)
    const float* __restrict__ posf_g, // (64,16)
    const float* __restrict__ bfused, // (32)
    const float* __restrict__ Wbond,  // (16)
    const float* __restrict__ bbond,  // (1)
    const float* __restrict__ Wdmg,   // (16)
    const float* __restrict__ bdmg,   // (1)
    float* __restrict__ wout)         // (B*NH*T, 64)
{
    __shared__ float2 dwin[16][68];   // [c2][row], rows t0-63 .. t0+3
    __shared__ float sbd[16];         // b_fused[16+e] (damage half)
    __shared__ float wbd[16];
    __shared__ float wdm[16];
    const int tid  = threadIdx.x;
    const int wave = tid >> 6;
    const int lane = tid & 63;
    const int bh = blockIdx.x >> 8;        // 0..31
    const int t0 = (blockIdx.x & 255) * 4; // 4 t-values per block
    const int h  = bh & 15;
    const int b  = bh >> 4;

    if (tid < 16) {
        sbd[tid] = bfused[16 + tid];
        wbd[tid] = Wbond[tid];
        wdm[tid] = Wdmg[tid];
    }
    // Stage 67 rows x 16 float2 of dproj (this head), transposed.
    const float* dbase = dproj + (size_t)(b * 1024) * 512 + h * 32;
    for (int n = tid; n < 67 * 16; n += 256) {
        const int r  = n >> 4;
        const int c2 = n & 15;
        int grow = t0 - 63 + r;
        grow = grow < 0 ? 0 : grow;
        dwin[c2][r] = *reinterpret_cast<const float2*>(dbase + (size_t)grow * 512 + c2 * 2);
    }
    // posf for this lane (j = lane), pre-summed with b_fused[0:16].
    float sbp[16];
    {
        const float4 p0 = *reinterpret_cast<const float4*>(posf_g + lane * 16);
        const float4 p1 = *reinterpret_cast<const float4*>(posf_g + lane * 16 + 4);
        const float4 p2 = *reinterpret_cast<const float4*>(posf_g + lane * 16 + 8);
        const float4 p3 = *reinterpret_cast<const float4*>(posf_g + lane * 16 + 12);
        const float* pp = (const float*)&p0;
        sbp[0] = p0.x; sbp[1] = p0.y; sbp[2] = p0.z; sbp[3] = p0.w;
        sbp[4] = p1.x; sbp[5] = p1.y; sbp[6] = p1.z; sbp[7] = p1.w;
        sbp[8] = p2.x; sbp[9] = p2.y; sbp[10] = p2.z; sbp[11] = p2.w;
        sbp[12] = p3.x; sbp[13] = p3.y; sbp[14] = p3.z; sbp[15] = p3.w;
        (void)pp;
        #pragma unroll
        for (int e = 0; e < 16; ++e) sbp[e] += bfused[e];
    }
    __syncthreads();

    const int t = t0 + wave;
    const int tsrc = t + lane - 63;
    const int rw = wave + lane;       // window row for this lane
    const int rt = wave + 63;         // window row of t itself (uniform)

    float bond = bbond[0];
    #pragma unroll
    for (int e2 = 0; e2 < 8; ++e2) {
        const float2 a = dwin[e2][rw];
        const float2 c = dwin[e2][rt];
        bond += gelu_fast(a.x - c.x + sbp[e2 * 2 + 0]) * wbd[e2 * 2 + 0];
        bond += gelu_fast(a.y - c.y + sbp[e2 * 2 + 1]) * wbd[e2 * 2 + 1];
    }
    float dmg = bdmg[0];
    #pragma unroll
    for (int e2 = 8; e2 < 16; ++e2) {
        const float2 a = dwin[e2][rw];
        const float2 c = dwin[e2][rt];
        const int e = (e2 - 8) * 2;
        dmg += gelu_fast(a.x - c.x + sbd[e + 0]) * wdm[e + 0];
        dmg += gelu_fast(a.y - c.y + sbd[e + 1]) * wdm[e + 1];
    }
    const float damage = __builtin_amdgcn_rcpf(1.0f + __expf(-dmg));
    float logit = bond - 10.0f * damage;
    if (tsrc < 0) logit = -INFINITY;

    float m = logit;
    #pragma unroll
    for (int o = 32; o; o >>= 1) m = fmaxf(m, __shfl_xor(m, o));
    const float p = __expf(logit - m);
    float ssum = p;
    #pragma unroll
    for (int o = 32; o; o >>= 1) ssum += __shfl_xor(ssum, o);
    wout[(size_t)(bh * 1024 + t) * 64 + lane] = p * __builtin_amdgcn_rcpf(ssum);
}

// One block per (b,h,64-row t-tile); writes attn directly as bf16 for cproj.
__global__ __launch_bounds__(256) void pv_kernel(
    const float* __restrict__ val,    // (B*T, C=1024)
    const float* __restrict__ w,      // (B*NH*T, 64)
    ushort* __restrict__ attnb)       // (B*T, C=1024) bf16
{
    __shared__ float Vs[127][64];
    __shared__ float Ws[64][65];
    const int tid = threadIdx.x;
    const int bh = blockIdx.x >> 4;
    const int t0 = (blockIdx.x & 15) * 64;
    const int b  = bh >> 4;
    const int h  = bh & 15;

    for (int n = tid * 4; n < 127 * 64; n += 256 * 4) {
        const int r = n >> 6;
        const int c = n & 63;
        int gr = t0 + r - 63;
        gr = gr < 0 ? 0 : gr;
        *reinterpret_cast<float4*>(&Vs[r][c]) =
            *reinterpret_cast<const float4*>(
                val + (size_t)(b * 1024 + gr) * 1024 + h * 64 + c);
    }
    for (int n = tid; n < 64 * 64; n += 256)
        Ws[n >> 6][n & 63] = w[((size_t)bh * 1024 + t0 + (n >> 6)) * 64 + (n & 63)];
    __syncthreads();

    const int k = tid & 63;
    const int tiBase = (tid >> 6) * 16;
    #pragma unroll
    for (int i = 0; i < 16; ++i) {
        const int ti = tiBase + i;
        float acc = 0.f;
        for (int jj = 0; jj < 64; ++jj)
            acc += Ws[ti][jj] * Vs[ti + jj][k];
        attnb[(size_t)(b * 1024 + t0 + ti) * 1024 + h * 64 + k] = f2bf(acc);
    }
}

extern "C" void kernel_launch(void* const* d_in, const int* in_sizes, int n_in,
                              void* d_out, int out_size, void* d_ws, size_t ws_size,
                              hipStream_t stream) {
    const float* x       = (const float*)d_in[0];
    const float* W_disp  = (const float*)d_in[1];
    const float* W_val   = (const float*)d_in[3];
    const float* b_val   = (const float*)d_in[4];
    const float* rel     = (const float*)d_in[5];
    const float* W_fused = (const float*)d_in[6];
    const float* b_fused = (const float*)d_in[7];
    const float* W_pos   = (const float*)d_in[8];
    const float* W_bond  = (const float*)d_in[9];
    const float* b_bond  = (const float*)d_in[10];
    const float* W_dmg   = (const float*)d_in[11];
    const float* b_dmg   = (const float*)d_in[12];
    const float* W_cproj = (const float*)d_in[13];
    const float* b_cproj = (const float*)d_in[14];
    float* out = (float*)d_out;

    // ws: xb 4MB | WvT 2MB | WcT 2MB | WcombT 1MB | dproj 4MB (aliased by
    // attnb after weights_kernel) | val 8MB | wbuf 8MB | posf 4KB
    ushort* xb      = (ushort*)d_ws;
    ushort* WvT     = xb + 2048 * 1024;
    ushort* WcT     = WvT + 1024 * 1024;
    ushort* WcombT  = WcT + 1024 * 1024;
    float*  dproj   = (float*)(WcombT + 512 * 1024);
    ushort* attnb   = (ushort*)dproj;            // alias: dproj dead before pv
    float*  val     = dproj + 2048 * 512;
    float*  wbuf    = val + 2048 * 1024;
    float*  posf    = wbuf + 32768 * 64;

    dim3 blk(256);
    fold_kernel<<<dim3(2049), blk, 0, stream>>>(
        W_disp, W_fused, rel, W_pos, WcombT, posf);
    cast_kernel<<<dim3(2048), blk, 0, stream>>>(x, xb, 2048 * 1024 / 4);
    tcast_kernel<<<dim3(16, 16), blk, 0, stream>>>(W_val, WvT, 1024, 1024);
    tcast_kernel<<<dim3(16, 16), blk, 0, stream>>>(W_cproj, WcT, 1024, 1024);

    gemm_bf16_kernel<<<dim3(512 / 64, 2048 / 64), blk, 0, stream>>>(
        xb, WcombT, nullptr, dproj, 2048, 512, 1024, 0);
    gemm_bf16_kernel<<<dim3(1024 / 64, 2048 / 64), blk, 0, stream>>>(
        xb, WvT, b_val, val, 2048, 1024, 1024, 1);
    weights_kernel<<<dim3(8192), blk, 0, stream>>>(
        dproj, posf, b_fused, W_bond, b_bond, W_dmg, b_dmg, wbuf);
    pv_kernel<<<dim3(512), blk, 0, stream>>>(val, wbuf, attnb);
    gemm_bf16_kernel<<<dim3(1024 / 64, 2048 / 64), blk, 0, stream>>>(
        attnb, WcT, b_cproj, out, 2048, 1024, 1024, 1);
}

// Round 6
// 102.769 us; speedup vs baseline: 9.8728x; 1.1279x over previous
//
#include <hip/hip_runtime.h>
#include <math.h>

// Problem constants: B=2, T=1024, C=1024, NH=16, HS=64, BD=16, HORIZON=64.

typedef __attribute__((ext_vector_type(4))) float f32x4;
typedef __attribute__((ext_vector_type(8))) __bf16 bf16x8;

__device__ __forceinline__ ushort f2bf(float f) {
    union { float f; unsigned u; } v; v.f = f;
    const unsigned r = v.u + 0x7fffu + ((v.u >> 16) & 1u);   // RNE
    return (ushort)(r >> 16);
}

// gelu tanh-form: max abs err ~1e-3, fine vs 6.7e-2 threshold.
__device__ __forceinline__ float gelu_fast(float z) {
    const float a = -1.5957691216057308f * z * fmaf(0.044715f, z * z, 1.0f);
    return z * __builtin_amdgcn_rcpf(1.0f + __expf(a));
}

// ---------------- bf16 MFMA GEMM ----------------
// C(M,N) = A(M,K)bf16 @ B(K,N) + bias, B pre-transposed Bt(N,K)bf16.
// 64x64 tile, BK=64, 4 waves (2x2 quadrants of 32x32), 16x16x32 MFMA.
// global_load_lds width=16 staging; T2 XOR swizzle both-sides (rule #21).
// biasMode: 0 none, 1 bias[col], 2 bias[row]. outBf16: C is ushort bf16.
__global__ __launch_bounds__(256) void gemm_bf16_kernel(
    const ushort* __restrict__ A,    // (M,K) bf16
    const ushort* __restrict__ Bt,   // (N,K) bf16
    const float* __restrict__ bias,
    void* __restrict__ Cout,
    int M, int N, int K, int biasMode, int outBf16)
{
    __shared__ ushort As[64 * 64];   // [row][k] swizzled, 8 KB
    __shared__ ushort Bs[64 * 64];   // [n][k]   swizzled, 8 KB
    const int tid  = threadIdx.x;
    const int wave = tid >> 6;
    const int lane = tid & 63;
    const int rowbase = blockIdx.y * 64;
    const int colbase = blockIdx.x * 64;
    const int wr = wave >> 1;
    const int wc = wave & 1;

    f32x4 acc[2][2] = {};

    for (int k0 = 0; k0 < K; k0 += 64) {
        #pragma unroll
        for (int i = 0; i < 2; ++i) {
            const int p   = (i * 4 + wave) * 64 + lane;   // 0..511
            const int row = p >> 3;
            const int kc  = (p & 7) ^ (row & 7);          // pre-swizzled source
            const ushort* srcA = A + (size_t)(rowbase + row) * K + k0 + kc * 8;
            __builtin_amdgcn_global_load_lds(
                (const __attribute__((address_space(1))) void*)srcA,
                (__attribute__((address_space(3))) void*)(As + (size_t)p * 8),
                16, 0, 0);
            const ushort* srcB = Bt + (size_t)(colbase + row) * K + k0 + kc * 8;
            __builtin_amdgcn_global_load_lds(
                (const __attribute__((address_space(1))) void*)srcB,
                (__attribute__((address_space(3))) void*)(Bs + (size_t)p * 8),
                16, 0, 0);
        }
        __syncthreads();

        #pragma unroll
        for (int kk = 0; kk < 2; ++kk) {
            const int kb = kk * 32 + (lane >> 4) * 8;
            bf16x8 a[2], b[2];
            #pragma unroll
            for (int ni = 0; ni < 2; ++ni) {
                const int n = wc * 32 + ni * 16 + (lane & 15);
                int off = (n * 128 + kb * 2) ^ ((n & 7) << 4);
                b[ni] = *(const bf16x8*)((const char*)Bs + off);
            }
            #pragma unroll
            for (int mi = 0; mi < 2; ++mi) {
                const int r = wr * 32 + mi * 16 + (lane & 15);
                int off = (r * 128 + kb * 2) ^ ((r & 7) << 4);
                a[mi] = *(const bf16x8*)((const char*)As + off);
            }
            #pragma unroll
            for (int mi = 0; mi < 2; ++mi)
                #pragma unroll
                for (int ni = 0; ni < 2; ++ni)
                    acc[mi][ni] = __builtin_amdgcn_mfma_f32_16x16x32_bf16(
                        a[mi], b[ni], acc[mi][ni], 0, 0, 0);
        }
        __syncthreads();
    }

    #pragma unroll
    for (int mi = 0; mi < 2; ++mi)
        #pragma unroll
        for (int ni = 0; ni < 2; ++ni) {
            const int col = colbase + wc * 32 + ni * 16 + (lane & 15);
            const float bvc = (biasMode == 1) ? bias[col] : 0.0f;
            #pragma unroll
            for (int r = 0; r < 4; ++r) {
                const int row = rowbase + wr * 32 + mi * 16 + (lane >> 4) * 4 + r;
                float v = acc[mi][ni][r] + bvc;
                if (biasMode == 2) v += bias[row];
                if (outBf16)
                    ((ushort*)Cout)[(size_t)row * N + col] = f2bf(v);
                else
                    ((float*)Cout)[(size_t)row * N + col] = v;
            }
        }
}

// fp32 -> bf16 cast, 4 elems/thread.
__global__ __launch_bounds__(256) void cast_kernel(
    const float* __restrict__ in, ushort* __restrict__ outp, int nvec4)
{
    const int idx = blockIdx.x * 256 + threadIdx.x;
    if (idx < nvec4) {
        const float4 v = reinterpret_cast<const float4*>(in)[idx];
        ushort4 o; o.x = f2bf(v.x); o.y = f2bf(v.y); o.z = f2bf(v.z); o.w = f2bf(v.w);
        reinterpret_cast<ushort4*>(outp)[idx] = o;
    }
}

// W (K,N) fp32 row-major -> Wt (N,K) bf16 row-major. 64x64 LDS transpose.
__global__ __launch_bounds__(256) void tcast_kernel(
    const float* __restrict__ W, ushort* __restrict__ Wt, int K, int N)
{
    __shared__ float tile[64][65];
    const int tid = threadIdx.x;
    const int n0 = blockIdx.x * 64;
    const int k0 = blockIdx.y * 64;
    #pragma unroll
    for (int i = 0; i < 4; ++i) {
        const int idx = tid + i * 256;
        const int r = idx >> 4;
        const int c = (idx & 15) << 2;
        const float4 v = *reinterpret_cast<const float4*>(
            W + (size_t)(k0 + r) * N + n0 + c);
        tile[r][c] = v.x; tile[r][c + 1] = v.y; tile[r][c + 2] = v.z; tile[r][c + 3] = v.w;
    }
    __syncthreads();
    #pragma unroll
    for (int i = 0; i < 4; ++i) {
        const int idx = tid + i * 256;
        const int n = idx >> 4;
        const int c = (idx & 15) << 2;
        ushort4 o;
        o.x = f2bf(tile[c][n]);     o.y = f2bf(tile[c + 1][n]);
        o.z = f2bf(tile[c + 2][n]); o.w = f2bf(tile[c + 3][n]);
        *reinterpret_cast<ushort4*>(Wt + (size_t)(n0 + n) * K + k0 + c) = o;
    }
}

// Folds W_disp@W_fused -> W_combT (512,1024) bf16; posf = rel@W_pos.
__global__ __launch_bounds__(256) void fold_kernel(
    const float* __restrict__ W_disp,  // (1024,256)
    const float* __restrict__ W_fused, // (16,32)
    const float* __restrict__ rel,     // (64,16)
    const float* __restrict__ Wpos,    // (16,16)
    ushort* __restrict__ W_combT,      // (512,1024) bf16 [cc][r]
    float* __restrict__ posf)          // (64,16)
{
    __shared__ float wfs[512];
    const int bid = blockIdx.x, tid = threadIdx.x;
    if (bid < 2048) {
        for (int i = tid; i < 512; i += 256) wfs[i] = W_fused[i];
        __syncthreads();
        const int idx = bid * 256 + tid;   // cc*1024 + r
        const int cc = idx >> 10;
        const int r  = idx & 1023;
        const int h = cc >> 5, e = cc & 31;
        const float* wd = W_disp + r * 256 + h * 16;
        float s = 0.f;
        #pragma unroll
        for (int d = 0; d < 16; ++d) s += wd[d] * wfs[d * 32 + e];
        W_combT[idx] = f2bf(s);
    } else {
        for (int n = tid; n < 1024; n += 256) {
            const int j = n >> 4, e = n & 15;
            float s = 0.f;
            #pragma unroll
            for (int k = 0; k < 16; ++k) s += rel[j * 16 + k] * Wpos[k * 16 + e];
            posf[n] = s;
        }
    }
}

// Block = one (b,h) x 4 consecutive t (one wave per t). dproj window staged
// transposed in LDS as float2[16][68]; posf in regs. Writes bf16 weights.
__global__ __launch_bounds__(256) void weights_kernel(
    const float* __restrict__ dproj,  // (B*T, 512)
    const float* __restrict__ posf_g, // (64,16)
    const float* __restrict__ bfused, // (32)
    const float* __restrict__ Wbond,  // (16)
    const float* __restrict__ bbond,  // (1)
    const float* __restrict__ Wdmg,   // (16)
    const float* __restrict__ bdmg,   // (1)
    ushort* __restrict__ wout)        // (B*NH*T, 64) bf16
{
    __shared__ float2 dwin[16][68];   // [c2][row], rows t0-63 .. t0+3
    __shared__ float sbd[16];
    __shared__ float wbd[16];
    __shared__ float wdm[16];
    const int tid  = threadIdx.x;
    const int wave = tid >> 6;
    const int lane = tid & 63;
    const int bh = blockIdx.x >> 8;
    const int t0 = (blockIdx.x & 255) * 4;
    const int h  = bh & 15;
    const int b  = bh >> 4;

    if (tid < 16) {
        sbd[tid] = bfused[16 + tid];
        wbd[tid] = Wbond[tid];
        wdm[tid] = Wdmg[tid];
    }
    const float* dbase = dproj + (size_t)(b * 1024) * 512 + h * 32;
    for (int n = tid; n < 67 * 16; n += 256) {
        const int r  = n >> 4;
        const int c2 = n & 15;
        int grow = t0 - 63 + r;
        grow = grow < 0 ? 0 : grow;
        dwin[c2][r] = *reinterpret_cast<const float2*>(dbase + (size_t)grow * 512 + c2 * 2);
    }
    float sbp[16];
    {
        const float4 p0 = *reinterpret_cast<const float4*>(posf_g + lane * 16);
        const float4 p1 = *reinterpret_cast<const float4*>(posf_g + lane * 16 + 4);
        const float4 p2 = *reinterpret_cast<const float4*>(posf_g + lane * 16 + 8);
        const float4 p3 = *reinterpret_cast<const float4*>(posf_g + lane * 16 + 12);
        sbp[0] = p0.x; sbp[1] = p0.y; sbp[2] = p0.z; sbp[3] = p0.w;
        sbp[4] = p1.x; sbp[5] = p1.y; sbp[6] = p1.z; sbp[7] = p1.w;
        sbp[8] = p2.x; sbp[9] = p2.y; sbp[10] = p2.z; sbp[11] = p2.w;
        sbp[12] = p3.x; sbp[13] = p3.y; sbp[14] = p3.z; sbp[15] = p3.w;
        #pragma unroll
        for (int e = 0; e < 16; ++e) sbp[e] += bfused[e];
    }
    __syncthreads();

    const int t = t0 + wave;
    const int tsrc = t + lane - 63;
    const int rw = wave + lane;
    const int rt = wave + 63;

    float bond = bbond[0];
    #pragma unroll
    for (int e2 = 0; e2 < 8; ++e2) {
        const float2 a = dwin[e2][rw];
        const float2 c = dwin[e2][rt];
        bond += gelu_fast(a.x - c.x + sbp[e2 * 2 + 0]) * wbd[e2 * 2 + 0];
        bond += gelu_fast(a.y - c.y + sbp[e2 * 2 + 1]) * wbd[e2 * 2 + 1];
    }
    float dmg = bdmg[0];
    #pragma unroll
    for (int e2 = 8; e2 < 16; ++e2) {
        const float2 a = dwin[e2][rw];
        const float2 c = dwin[e2][rt];
        const int e = (e2 - 8) * 2;
        dmg += gelu_fast(a.x - c.x + sbd[e + 0]) * wdm[e + 0];
        dmg += gelu_fast(a.y - c.y + sbd[e + 1]) * wdm[e + 1];
    }
    const float damage = __builtin_amdgcn_rcpf(1.0f + __expf(-dmg));
    float logit = bond - 10.0f * damage;
    if (tsrc < 0) logit = -INFINITY;

    float m = logit;
    #pragma unroll
    for (int o = 32; o; o >>= 1) m = fmaxf(m, __shfl_xor(m, o));
    const float p = __expf(logit - m);
    float ssum = p;
    #pragma unroll
    for (int o = 32; o; o >>= 1) ssum += __shfl_xor(ssum, o);
    wout[(size_t)(bh * 1024 + t) * 64 + lane] = f2bf(p * __builtin_amdgcn_rcpf(ssum));
}

// MFMA PV: per (b,h,64-t tile), out(64x64) = P(64x128) @ V_win(128x64).
// P is the banded weight matrix (P[ti][ti+jj+1] = w[ti][jj], zero elsewhere);
// V_win staged from valT (channel-major) via global_load_lds; both LDS tiles
// XOR-swizzled. Window base t0-64 keeps all 16B chunks aligned; at t0=0 the
// fully-OOB chunks clamp to t=0, whose P entries are exactly 0 (softmax mask).
__global__ __launch_bounds__(256) void pv_kernel(
    const ushort* __restrict__ valT,  // (C=1024, B*T=2048) bf16
    const ushort* __restrict__ w,     // (B*NH*T, 64) bf16
    ushort* __restrict__ attnb)       // (B*T, 1024) bf16
{
    __shared__ ushort Ps[64 * 128];   // [ti][r] swizzled, 16 KB
    __shared__ ushort Vs[64 * 128];   // [c][r]  swizzled, 16 KB
    const int tid  = threadIdx.x;
    const int wave = tid >> 6;
    const int lane = tid & 63;
    const int bh = blockIdx.x >> 4;
    const int t0 = (blockIdx.x & 15) * 64;
    const int b  = bh >> 4;
    const int h  = bh & 15;

    // stage Vs: 64 rows x 16 chunks of 16B (8 bf16 times each)
    #pragma unroll
    for (int i = 0; i < 4; ++i) {
        const int p = i * 256 + tid;
        const int c = p >> 4, q = p & 15;
        const int kc = q ^ (c & 7);                       // pre-swizzled source
        int tt = t0 - 64 + kc * 8;
        tt = tt < 0 ? 0 : tt;
        const ushort* src = valT + (size_t)(h * 64 + c) * 2048 + b * 1024 + tt;
        __builtin_amdgcn_global_load_lds(
            (const __attribute__((address_space(1))) void*)src,
            (__attribute__((address_space(3))) void*)(Vs + (size_t)p * 8),
            16, 0, 0);
    }
    // zero P
    #pragma unroll
    for (int i = 0; i < 4; ++i)
        reinterpret_cast<uint4*>(Ps)[i * 256 + tid] = uint4{0, 0, 0, 0};
    __syncthreads();
    // scatter band: P[ti][ti+jj+1] = w[ti][jj]
    #pragma unroll
    for (int i = 0; i < 16; ++i) {
        const int n  = i * 256 + tid;
        const int ti = n >> 6, jj = n & 63;
        const ushort wv = w[((size_t)bh * 1024 + t0 + ti) * 64 + jj];
        const int off = (ti * 256 + (ti + jj + 1) * 2) ^ ((ti & 7) << 4);
        *(ushort*)((char*)Ps + off) = wv;
    }
    __syncthreads();

    const int wr = wave >> 1;
    const int wc = wave & 1;
    f32x4 acc[2][2] = {};
    #pragma unroll
    for (int kk = 0; kk < 4; ++kk) {
        const int kb = kk * 32 + (lane >> 4) * 8;
        bf16x8 a[2], bv[2];
        #pragma unroll
        for (int ni = 0; ni < 2; ++ni) {
            const int cc = wc * 32 + ni * 16 + (lane & 15);
            const int off = (cc * 256 + kb * 2) ^ ((cc & 7) << 4);
            bv[ni] = *(const bf16x8*)((const char*)Vs + off);
        }
        #pragma unroll
        for (int mi = 0; mi < 2; ++mi) {
            const int rr = wr * 32 + mi * 16 + (lane & 15);
            const int off = (rr * 256 + kb * 2) ^ ((rr & 7) << 4);
            a[mi] = *(const bf16x8*)((const char*)Ps + off);
        }
        #pragma unroll
        for (int mi = 0; mi < 2; ++mi)
            #pragma unroll
            for (int ni = 0; ni < 2; ++ni)
                acc[mi][ni] = __builtin_amdgcn_mfma_f32_16x16x32_bf16(
                    a[mi], bv[ni], acc[mi][ni], 0, 0, 0);
    }

    #pragma unroll
    for (int mi = 0; mi < 2; ++mi)
        #pragma unroll
        for (int ni = 0; ni < 2; ++ni) {
            const int c = wc * 32 + ni * 16 + (lane & 15);
            #pragma unroll
            for (int r = 0; r < 4; ++r) {
                const int trow = t0 + wr * 32 + mi * 16 + (lane >> 4) * 4 + r;
                attnb[(size_t)(b * 1024 + trow) * 1024 + h * 64 + c] =
                    f2bf(acc[mi][ni][r]);
            }
        }
}

extern "C" void kernel_launch(void* const* d_in, const int* in_sizes, int n_in,
                              void* d_out, int out_size, void* d_ws, size_t ws_size,
                              hipStream_t stream) {
    const float* x       = (const float*)d_in[0];
    const float* W_disp  = (const float*)d_in[1];
    const float* W_val   = (const float*)d_in[3];
    const float* b_val   = (const float*)d_in[4];
    const float* rel     = (const float*)d_in[5];
    const float* W_fused = (const float*)d_in[6];
    const float* b_fused = (const float*)d_in[7];
    const float* W_pos   = (const float*)d_in[8];
    const float* W_bond  = (const float*)d_in[9];
    const float* b_bond  = (const float*)d_in[10];
    const float* W_dmg   = (const float*)d_in[11];
    const float* b_dmg   = (const float*)d_in[12];
    const float* W_cproj = (const float*)d_in[13];
    const float* b_cproj = (const float*)d_in[14];
    float* out = (float*)d_out;

    // ws: xb 4MB | WvT 2MB | WcT 2MB | WcombT 1MB | dproj fp32 4MB (aliased
    // by attnb bf16 after weights_kernel) | valT bf16 4MB | wbuf bf16 4MB |
    // posf 4KB
    ushort* xb      = (ushort*)d_ws;
    ushort* WvT     = xb + 2048 * 1024;
    ushort* WcT     = WvT + 1024 * 1024;
    ushort* WcombT  = WcT + 1024 * 1024;
    float*  dproj   = (float*)(WcombT + 512 * 1024);
    ushort* attnb   = (ushort*)dproj;            // alias: dproj dead before pv
    ushort* valT    = (ushort*)(dproj + 2048 * 512);
    ushort* wbuf    = valT + 1024 * 2048;
    float*  posf    = (float*)(wbuf + 32768 * 64);

    dim3 blk(256);
    fold_kernel<<<dim3(2049), blk, 0, stream>>>(
        W_disp, W_fused, rel, W_pos, WcombT, posf);
    cast_kernel<<<dim3(2048), blk, 0, stream>>>(x, xb, 2048 * 1024 / 4);
    tcast_kernel<<<dim3(16, 16), blk, 0, stream>>>(W_val, WvT, 1024, 1024);
    tcast_kernel<<<dim3(16, 16), blk, 0, stream>>>(W_cproj, WcT, 1024, 1024);

    gemm_bf16_kernel<<<dim3(512 / 64, 2048 / 64), blk, 0, stream>>>(
        xb, WcombT, nullptr, dproj, 2048, 512, 1024, 0, 0);
    // valT = (x @ W_val + b_val)^T  via A=W_val^T (M=C), Bt=x (N=B*T), row-bias
    gemm_bf16_kernel<<<dim3(2048 / 64, 1024 / 64), blk, 0, stream>>>(
        WvT, xb, b_val, valT, 1024, 2048, 1024, 2, 1);
    weights_kernel<<<dim3(8192), blk, 0, stream>>>(
        dproj, posf, b_fused, W_bond, b_bond, W_dmg, b_dmg, wbuf);
    pv_kernel<<<dim3(512), blk, 0, stream>>>(valT, wbuf, attnb);
    gemm_bf16_kernel<<<dim3(1024 / 64, 2048 / 64), blk, 0, stream>>>(
        attnb, WcT, b_cproj, out, 2048, 1024, 1024, 1, 0);
}

// Round 7
// 76.890 us; speedup vs baseline: 13.1957x; 1.3366x over previous
//
#include <hip/hip_runtime.h>
#include <math.h>

// Problem constants: B=2, T=1024, C=1024, NH=16, HS=64, BD=16, HORIZON=64.

typedef __attribute__((ext_vector_type(4))) float f32x4;
typedef __attribute__((ext_vector_type(8))) __bf16 bf16x8;

__device__ __forceinline__ ushort f2bf(float f) {
    union { float f; unsigned u; } v; v.f = f;
    const unsigned r = v.u + 0x7fffu + ((v.u >> 16) & 1u);   // RNE
    return (ushort)(r >> 16);
}

// gelu tanh-form: max abs err ~1e-3, fine vs 6.7e-2 threshold.
__device__ __forceinline__ float gelu_fast(float z) {
    const float a = -1.5957691216057308f * z * fmaf(0.044715f, z * z, 1.0f);
    return z * __builtin_amdgcn_rcpf(1.0f + __expf(a));
}

// ---------------- generic bf16 MFMA GEMM (64x64 tile) ----------------
// C(M,N) = A(M,K)bf16 @ B(K,N) + bias[col]; B pre-transposed Bt(N,K)bf16.
__global__ __launch_bounds__(256) void gemm_bf16_kernel(
    const ushort* __restrict__ A, const ushort* __restrict__ Bt,
    const float* __restrict__ bias, float* __restrict__ C,
    int M, int N, int K)
{
    __shared__ ushort As[64 * 64];
    __shared__ ushort Bs[64 * 64];
    const int tid  = threadIdx.x;
    const int wave = tid >> 6;
    const int lane = tid & 63;
    const int rowbase = blockIdx.y * 64;
    const int colbase = blockIdx.x * 64;
    const int wr = wave >> 1;
    const int wc = wave & 1;

    f32x4 acc[2][2] = {};

    for (int k0 = 0; k0 < K; k0 += 64) {
        #pragma unroll
        for (int i = 0; i < 2; ++i) {
            const int p   = i * 256 + tid;                // 0..511
            const int row = p >> 3;
            const int kc  = (p & 7) ^ (row & 7);          // pre-swizzled source
            const ushort* srcA = A + (size_t)(rowbase + row) * K + k0 + kc * 8;
            __builtin_amdgcn_global_load_lds(
                (const __attribute__((address_space(1))) void*)srcA,
                (__attribute__((address_space(3))) void*)(As + (size_t)p * 8),
                16, 0, 0);
            const ushort* srcB = Bt + (size_t)(colbase + row) * K + k0 + kc * 8;
            __builtin_amdgcn_global_load_lds(
                (const __attribute__((address_space(1))) void*)srcB,
                (__attribute__((address_space(3))) void*)(Bs + (size_t)p * 8),
                16, 0, 0);
        }
        __syncthreads();

        #pragma unroll
        for (int kk = 0; kk < 2; ++kk) {
            const int kb = kk * 32 + (lane >> 4) * 8;
            bf16x8 a[2], b[2];
            #pragma unroll
            for (int ni = 0; ni < 2; ++ni) {
                const int n = wc * 32 + ni * 16 + (lane & 15);
                const int off = (n * 128 + kb * 2) ^ ((n & 7) << 4);
                b[ni] = *(const bf16x8*)((const char*)Bs + off);
            }
            #pragma unroll
            for (int mi = 0; mi < 2; ++mi) {
                const int r = wr * 32 + mi * 16 + (lane & 15);
                const int off = (r * 128 + kb * 2) ^ ((r & 7) << 4);
                a[mi] = *(const bf16x8*)((const char*)As + off);
            }
            #pragma unroll
            for (int mi = 0; mi < 2; ++mi)
                #pragma unroll
                for (int ni = 0; ni < 2; ++ni)
                    acc[mi][ni] = __builtin_amdgcn_mfma_f32_16x16x32_bf16(
                        a[mi], b[ni], acc[mi][ni], 0, 0, 0);
        }
        __syncthreads();
    }

    #pragma unroll
    for (int mi = 0; mi < 2; ++mi)
        #pragma unroll
        for (int ni = 0; ni < 2; ++ni) {
            const int col = colbase + wc * 32 + ni * 16 + (lane & 15);
            const float bvc = bias[col];
            #pragma unroll
            for (int r = 0; r < 4; ++r) {
                const int row = rowbase + wr * 32 + mi * 16 + (lane >> 4) * 4 + r;
                C[(size_t)row * N + col] = acc[mi][ni][r] + bvc;
            }
        }
}

// ---------------- fused QV GEMM (128x64 tile) ----------------
// A_cat(1536,1024)bf16 rows: [0,512)=W_combT, [512,1536)=W_valT.
// Bt = xb (2048,1024). Out rows <512 -> dprojT fp32 (512,2048);
// rows >=512 -> valT bf16 (1024,2048) + b_val[row-512]. Block-uniform split.
__global__ __launch_bounds__(256) void gemm_qv_kernel(
    const ushort* __restrict__ Acat,
    const ushort* __restrict__ xb,
    const float* __restrict__ b_val,
    float* __restrict__ dprojT,
    ushort* __restrict__ valT)
{
    __shared__ ushort As[128 * 64];  // 16 KB
    __shared__ ushort Bs[64 * 64];   //  8 KB
    const int tid  = threadIdx.x;
    const int wave = tid >> 6;
    const int lane = tid & 63;
    const int rowbase = blockIdx.y * 128;
    const int colbase = blockIdx.x * 64;
    const int wr = wave >> 1;        // 64-row half
    const int wc = wave & 1;         // 32-col half

    f32x4 acc[4][2] = {};

    for (int k0 = 0; k0 < 1024; k0 += 64) {
        #pragma unroll
        for (int i = 0; i < 4; ++i) {
            const int p   = i * 256 + tid;                // 0..1023
            const int row = p >> 3;
            const int kc  = (p & 7) ^ (row & 7);
            const ushort* srcA = Acat + (size_t)(rowbase + row) * 1024 + k0 + kc * 8;
            __builtin_amdgcn_global_load_lds(
                (const __attribute__((address_space(1))) void*)srcA,
                (__attribute__((address_space(3))) void*)(As + (size_t)p * 8),
                16, 0, 0);
        }
        #pragma unroll
        for (int i = 0; i < 2; ++i) {
            const int p   = i * 256 + tid;                // 0..511
            const int row = p >> 3;
            const int kc  = (p & 7) ^ (row & 7);
            const ushort* srcB = xb + (size_t)(colbase + row) * 1024 + k0 + kc * 8;
            __builtin_amdgcn_global_load_lds(
                (const __attribute__((address_space(1))) void*)srcB,
                (__attribute__((address_space(3))) void*)(Bs + (size_t)p * 8),
                16, 0, 0);
        }
        __syncthreads();

        #pragma unroll
        for (int kk = 0; kk < 2; ++kk) {
            const int kb = kk * 32 + (lane >> 4) * 8;
            bf16x8 a[4], b[2];
            #pragma unroll
            for (int ni = 0; ni < 2; ++ni) {
                const int n = wc * 32 + ni * 16 + (lane & 15);
                const int off = (n * 128 + kb * 2) ^ ((n & 7) << 4);
                b[ni] = *(const bf16x8*)((const char*)Bs + off);
            }
            #pragma unroll
            for (int mi = 0; mi < 4; ++mi) {
                const int r = wr * 64 + mi * 16 + (lane & 15);
                const int off = (r * 128 + kb * 2) ^ ((r & 7) << 4);
                a[mi] = *(const bf16x8*)((const char*)As + off);
            }
            #pragma unroll
            for (int mi = 0; mi < 4; ++mi)
                #pragma unroll
                for (int ni = 0; ni < 2; ++ni)
                    acc[mi][ni] = __builtin_amdgcn_mfma_f32_16x16x32_bf16(
                        a[mi], b[ni], acc[mi][ni], 0, 0, 0);
        }
        __syncthreads();
    }

    if (rowbase < 512) {
        #pragma unroll
        for (int mi = 0; mi < 4; ++mi)
            #pragma unroll
            for (int ni = 0; ni < 2; ++ni) {
                const int col = colbase + wc * 32 + ni * 16 + (lane & 15);
                #pragma unroll
                for (int r = 0; r < 4; ++r) {
                    const int row = rowbase + wr * 64 + mi * 16 + (lane >> 4) * 4 + r;
                    dprojT[(size_t)row * 2048 + col] = acc[mi][ni][r];
                }
            }
    } else {
        #pragma unroll
        for (int mi = 0; mi < 4; ++mi)
            #pragma unroll
            for (int ni = 0; ni < 2; ++ni) {
                const int col = colbase + wc * 32 + ni * 16 + (lane & 15);
                #pragma unroll
                for (int r = 0; r < 4; ++r) {
                    const int row = rowbase - 512 + wr * 64 + mi * 16 + (lane >> 4) * 4 + r;
                    valT[(size_t)row * 2048 + col] = f2bf(acc[mi][ni][r] + b_val[row]);
                }
            }
    }
}

// ---------------- fused prep ----------------
// blocks [0,2048): cast x -> xb bf16
// blocks [2048,2304): transpose-cast W_val -> Acat[512:1536]
// blocks [2304,2560): transpose-cast W_cproj -> WcT
// blocks [2560,4608): fold W_disp@W_fused -> Acat[0:512]
// block 4608: posf = rel@W_pos
__global__ __launch_bounds__(256) void prep_kernel(
    const float* __restrict__ x,
    const float* __restrict__ W_disp,
    const float* __restrict__ W_val,
    const float* __restrict__ W_cproj,
    const float* __restrict__ W_fused,
    const float* __restrict__ rel,
    const float* __restrict__ Wpos,
    ushort* __restrict__ xb,
    ushort* __restrict__ Acat,      // (1536,1024) bf16
    ushort* __restrict__ WcT,       // (1024,1024) bf16
    float* __restrict__ posf)       // (64,16)
{
    __shared__ float shmem[64 * 65];
    const int bid = blockIdx.x, tid = threadIdx.x;

    if (bid < 2048) {
        const int idx = bid * 256 + tid;
        const float4 v = reinterpret_cast<const float4*>(x)[idx];
        ushort4 o; o.x = f2bf(v.x); o.y = f2bf(v.y); o.z = f2bf(v.z); o.w = f2bf(v.w);
        reinterpret_cast<ushort4*>(xb)[idx] = o;
    } else if (bid < 2560) {
        const int isC = bid >= 2304;
        const int b2 = bid - (isC ? 2304 : 2048);
        const float* W = isC ? W_cproj : W_val;
        ushort* Wt = isC ? WcT : (Acat + 512 * 1024);
        const int n0 = (b2 & 15) * 64;
        const int k0 = (b2 >> 4) * 64;
        float (*tile)[65] = (float (*)[65])shmem;
        #pragma unroll
        for (int i = 0; i < 4; ++i) {
            const int idx = tid + i * 256;
            const int r = idx >> 4;
            const int c = (idx & 15) << 2;
            const float4 v = *reinterpret_cast<const float4*>(
                W + (size_t)(k0 + r) * 1024 + n0 + c);
            tile[r][c] = v.x; tile[r][c+1] = v.y; tile[r][c+2] = v.z; tile[r][c+3] = v.w;
        }
        __syncthreads();
        #pragma unroll
        for (int i = 0; i < 4; ++i) {
            const int idx = tid + i * 256;
            const int n = idx >> 4;
            const int c = (idx & 15) << 2;
            ushort4 o;
            o.x = f2bf(tile[c][n]);     o.y = f2bf(tile[c + 1][n]);
            o.z = f2bf(tile[c + 2][n]); o.w = f2bf(tile[c + 3][n]);
            *reinterpret_cast<ushort4*>(Wt + (size_t)(n0 + n) * 1024 + k0 + c) = o;
        }
    } else if (bid < 4608) {
        float* wfs = shmem;
        for (int i = tid; i < 512; i += 256) wfs[i] = W_fused[i];
        __syncthreads();
        const int idx = (bid - 2560) * 256 + tid;  // cc*1024 + r
        const int cc = idx >> 10;
        const int r  = idx & 1023;
        const int h = cc >> 5, e = cc & 31;
        const float* wd = W_disp + r * 256 + h * 16;
        float s = 0.f;
        #pragma unroll
        for (int d = 0; d < 16; ++d) s += wd[d] * wfs[d * 32 + e];
        Acat[idx] = f2bf(s);
    } else {
        for (int n = tid; n < 1024; n += 256) {
            const int j = n >> 4, e = n & 15;
            float s = 0.f;
            #pragma unroll
            for (int k = 0; k < 16; ++k) s += rel[j * 16 + k] * Wpos[k * 16 + e];
            posf[n] = s;
        }
    }
}

// Block = one (b,h) x 4 consecutive t (one wave per t). dprojT channel-major:
// staging reads 64 consecutive times per channel (coalesced). bf16 weights out.
__global__ __launch_bounds__(256) void weights_kernel(
    const float* __restrict__ dprojT, // (512, B*T=2048)
    const float* __restrict__ posf_g, // (64,16)
    const float* __restrict__ bfused, // (32)
    const float* __restrict__ Wbond,  // (16)
    const float* __restrict__ bbond,  // (1)
    const float* __restrict__ Wdmg,   // (16)
    const float* __restrict__ bdmg,   // (1)
    ushort* __restrict__ wout)        // (B*NH*T, 64) bf16
{
    __shared__ float dwin[32][68];    // [chan][row]: rows t0-63 .. t0+3
    __shared__ float sbd[16];
    __shared__ float wbd[16];
    __shared__ float wdm[16];
    const int tid  = threadIdx.x;
    const int wave = tid >> 6;
    const int lane = tid & 63;
    const int bh = blockIdx.x >> 8;
    const int t0 = (blockIdx.x & 255) * 4;
    const int h  = bh & 15;
    const int b  = bh >> 4;

    if (tid < 16) {
        sbd[tid] = bfused[16 + tid];
        wbd[tid] = Wbond[tid];
        wdm[tid] = Wdmg[tid];
    }
    const float* dbase = dprojT + (size_t)(h * 32) * 2048 + b * 1024;
    {
        const int r = tid & 63;
        int grow = t0 - 63 + r;
        grow = grow < 0 ? 0 : grow;
        #pragma unroll
        for (int i = 0; i < 8; ++i) {
            const int c = (tid >> 6) + i * 4;
            dwin[c][r] = dbase[(size_t)c * 2048 + grow];
        }
    }
    if (tid < 128) {
        const int c = tid >> 2;
        const int rs = tid & 3;
        if (rs < 3) {
            const int r = 64 + rs;
            int grow = t0 - 63 + r;
            // t0-63+64 >= 1 always; max t0=1020 -> 1023. no clamp needed
            dwin[c][r] = dbase[(size_t)c * 2048 + grow];
        }
    }
    float sbp[16];
    {
        const float4 p0 = *reinterpret_cast<const float4*>(posf_g + lane * 16);
        const float4 p1 = *reinterpret_cast<const float4*>(posf_g + lane * 16 + 4);
        const float4 p2 = *reinterpret_cast<const float4*>(posf_g + lane * 16 + 8);
        const float4 p3 = *reinterpret_cast<const float4*>(posf_g + lane * 16 + 12);
        sbp[0] = p0.x; sbp[1] = p0.y; sbp[2]  = p0.z; sbp[3]  = p0.w;
        sbp[4] = p1.x; sbp[5] = p1.y; sbp[6]  = p1.z; sbp[7]  = p1.w;
        sbp[8] = p2.x; sbp[9] = p2.y; sbp[10] = p2.z; sbp[11] = p2.w;
        sbp[12] = p3.x; sbp[13] = p3.y; sbp[14] = p3.z; sbp[15] = p3.w;
        #pragma unroll
        for (int e = 0; e < 16; ++e) sbp[e] += bfused[e];
    }
    __syncthreads();

    const int t = t0 + wave;
    const int tsrc = t + lane - 63;
    const int rw = wave + lane;
    const int rt = wave + 63;

    float bond = bbond[0];
    float dmg  = bdmg[0];
    #pragma unroll
    for (int e = 0; e < 16; ++e) {
        bond += gelu_fast(dwin[e][rw] - dwin[e][rt] + sbp[e]) * wbd[e];
        dmg  += gelu_fast(dwin[16 + e][rw] - dwin[16 + e][rt] + sbd[e]) * wdm[e];
    }
    const float damage = __builtin_amdgcn_rcpf(1.0f + __expf(-dmg));
    float logit = bond - 10.0f * damage;
    if (tsrc < 0) logit = -INFINITY;

    float m = logit;
    #pragma unroll
    for (int o = 32; o; o >>= 1) m = fmaxf(m, __shfl_xor(m, o));
    const float p = __expf(logit - m);
    float ssum = p;
    #pragma unroll
    for (int o = 32; o; o >>= 1) ssum += __shfl_xor(ssum, o);
    wout[(size_t)(bh * 1024 + t) * 64 + lane] = f2bf(p * __builtin_amdgcn_rcpf(ssum));
}

// MFMA PV: per (b,h,64-t tile), out(64x64) = P(64x128) @ V_win(128x64).
__global__ __launch_bounds__(256) void pv_kernel(
    const ushort* __restrict__ valT,  // (C=1024, B*T=2048) bf16
    const ushort* __restrict__ w,     // (B*NH*T, 64) bf16
    ushort* __restrict__ attnb)       // (B*T, 1024) bf16
{
    __shared__ ushort Ps[64 * 128];   // [ti][r] swizzled, 16 KB
    __shared__ ushort Vs[64 * 128];   // [c][r]  swizzled, 16 KB
    const int tid  = threadIdx.x;
    const int wave = tid >> 6;
    const int lane = tid & 63;
    const int bh = blockIdx.x >> 4;
    const int t0 = (blockIdx.x & 15) * 64;
    const int b  = bh >> 4;
    const int h  = bh & 15;

    #pragma unroll
    for (int i = 0; i < 4; ++i) {
        const int p = i * 256 + tid;
        const int c = p >> 4, q = p & 15;
        const int kc = q ^ (c & 7);
        int tt = t0 - 64 + kc * 8;
        tt = tt < 0 ? 0 : tt;
        const ushort* src = valT + (size_t)(h * 64 + c) * 2048 + b * 1024 + tt;
        __builtin_amdgcn_global_load_lds(
            (const __attribute__((address_space(1))) void*)src,
            (__attribute__((address_space(3))) void*)(Vs + (size_t)p * 8),
            16, 0, 0);
    }
    #pragma unroll
    for (int i = 0; i < 4; ++i)
        reinterpret_cast<uint4*>(Ps)[i * 256 + tid] = uint4{0, 0, 0, 0};
    __syncthreads();
    #pragma unroll
    for (int i = 0; i < 16; ++i) {
        const int n  = i * 256 + tid;
        const int ti = n >> 6, jj = n & 63;
        const ushort wv = w[((size_t)bh * 1024 + t0 + ti) * 64 + jj];
        const int off = (ti * 256 + (ti + jj + 1) * 2) ^ ((ti & 7) << 4);
        *(ushort*)((char*)Ps + off) = wv;
    }
    __syncthreads();

    const int wr = wave >> 1;
    const int wc = wave & 1;
    f32x4 acc[2][2] = {};
    #pragma unroll
    for (int kk = 0; kk < 4; ++kk) {
        const int kb = kk * 32 + (lane >> 4) * 8;
        bf16x8 a[2], bv[2];
        #pragma unroll
        for (int ni = 0; ni < 2; ++ni) {
            const int cc = wc * 32 + ni * 16 + (lane & 15);
            const int off = (cc * 256 + kb * 2) ^ ((cc & 7) << 4);
            bv[ni] = *(const bf16x8*)((const char*)Vs + off);
        }
        #pragma unroll
        for (int mi = 0; mi < 2; ++mi) {
            const int rr = wr * 32 + mi * 16 + (lane & 15);
            const int off = (rr * 256 + kb * 2) ^ ((rr & 7) << 4);
            a[mi] = *(const bf16x8*)((const char*)Ps + off);
        }
        #pragma unroll
        for (int mi = 0; mi < 2; ++mi)
            #pragma unroll
            for (int ni = 0; ni < 2; ++ni)
                acc[mi][ni] = __builtin_amdgcn_mfma_f32_16x16x32_bf16(
                    a[mi], bv[ni], acc[mi][ni], 0, 0, 0);
    }

    #pragma unroll
    for (int mi = 0; mi < 2; ++mi)
        #pragma unroll
        for (int ni = 0; ni < 2; ++ni) {
            const int c = wc * 32 + ni * 16 + (lane & 15);
            #pragma unroll
            for (int r = 0; r < 4; ++r) {
                const int trow = t0 + wr * 32 + mi * 16 + (lane >> 4) * 4 + r;
                attnb[(size_t)(b * 1024 + trow) * 1024 + h * 64 + c] =
                    f2bf(acc[mi][ni][r]);
            }
        }
}

extern "C" void kernel_launch(void* const* d_in, const int* in_sizes, int n_in,
                              void* d_out, int out_size, void* d_ws, size_t ws_size,
                              hipStream_t stream) {
    const float* x       = (const float*)d_in[0];
    const float* W_disp  = (const float*)d_in[1];
    const float* W_val   = (const float*)d_in[3];
    const float* b_val   = (const float*)d_in[4];
    const float* rel     = (const float*)d_in[5];
    const float* W_fused = (const float*)d_in[6];
    const float* b_fused = (const float*)d_in[7];
    const float* W_pos   = (const float*)d_in[8];
    const float* W_bond  = (const float*)d_in[9];
    const float* b_bond  = (const float*)d_in[10];
    const float* W_dmg   = (const float*)d_in[11];
    const float* b_dmg   = (const float*)d_in[12];
    const float* W_cproj = (const float*)d_in[13];
    const float* b_cproj = (const float*)d_in[14];
    float* out = (float*)d_out;

    // ws: Acat bf16 3MB | xb bf16 4MB | WcT bf16 2MB | dprojT fp32 4MB |
    // valT bf16 4MB | wbuf bf16 4MB | attnb bf16 4MB | posf 4KB
    ushort* Acat   = (ushort*)d_ws;
    ushort* xb     = Acat + 1536 * 1024;
    ushort* WcT    = xb + 2048 * 1024;
    float*  dprojT = (float*)(WcT + 1024 * 1024);
    ushort* valT   = (ushort*)(dprojT + 512 * 2048);
    ushort* wbuf   = valT + 1024 * 2048;
    ushort* attnb  = wbuf + 32768 * 64;
    float*  posf   = (float*)(attnb + 2048 * 1024);

    dim3 blk(256);
    prep_kernel<<<dim3(4609), blk, 0, stream>>>(
        x, W_disp, W_val, W_cproj, W_fused, rel, W_pos, xb, Acat, WcT, posf);
    gemm_qv_kernel<<<dim3(2048 / 64, 1536 / 128), blk, 0, stream>>>(
        Acat, xb, b_val, dprojT, valT);
    weights_kernel<<<dim3(8192), blk, 0, stream>>>(
        dprojT, posf, b_fused, W_bond, b_bond, W_dmg, b_dmg, wbuf);
    pv_kernel<<<dim3(512), blk, 0, stream>>>(valT, wbuf, attnb);
    gemm_bf16_kernel<<<dim3(1024 / 64, 2048 / 64), blk, 0, stream>>>(
        attnb, WcT, b_cproj, out, 2048, 1024, 1024);
}